// Round 11
// baseline (357.962 us; speedup 1.0000x reference)
//
#include <hip/hip_runtime.h>
#include <cstdint>
#include <cstddef>

typedef __bf16 bf16_t;
typedef __bf16 bf16x8 __attribute__((ext_vector_type(8)));
typedef float f32x4 __attribute__((ext_vector_type(4)));

// ---------------- conversions ----------------
__global__ void conv_k(const float* __restrict__ in, bf16_t* __restrict__ out, int n8) {
    int id = blockIdx.x * 256 + threadIdx.x;
    if (id >= n8) return;
    const float4* p = (const float4*)in;
    float4 a = p[2 * id], b = p[2 * id + 1];
    bf16x8 o;
    o[0] = (bf16_t)a.x; o[1] = (bf16_t)a.y; o[2] = (bf16_t)a.z; o[3] = (bf16_t)a.w;
    o[4] = (bf16_t)b.x; o[5] = (bf16_t)b.y; o[6] = (bf16_t)b.z; o[7] = (bf16_t)b.w;
    *(bf16x8*)(out + (size_t)id * 8) = o;
}

// x fp32 -> cols 0..127 of interleaved ha[N][256]
__global__ void conv_x_k(const float* __restrict__ in, bf16_t* __restrict__ ha, int n8) {
    int id = blockIdx.x * 256 + threadIdx.x;
    if (id >= n8) return;
    const float4* p = (const float4*)in;
    float4 a = p[2 * id], b = p[2 * id + 1];
    bf16x8 o;
    o[0] = (bf16_t)a.x; o[1] = (bf16_t)a.y; o[2] = (bf16_t)a.z; o[3] = (bf16_t)a.w;
    o[4] = (bf16_t)b.x; o[5] = (bf16_t)b.y; o[6] = (bf16_t)b.z; o[7] = (bf16_t)b.w;
    int row = id >> 4, ch = id & 15;
    *(bf16x8*)(ha + (size_t)row * 256 + ch * 8) = o;
}

// ---------------- merged weight: Wc = w1 @ W0, bcomb = w1 @ lin_b ----------------
__global__ void wcomb_k(const float* __restrict__ w1, const float* __restrict__ lin_w,
                        const float* __restrict__ lin_b, const float* __restrict__ eps_p,
                        bf16_t* __restrict__ wc, float* __restrict__ bcomb) {
    __shared__ float red[256];
    int c = blockIdx.x, t = threadIdx.x;
    const float* w1row = w1 + c * 256;
    float onepe = 1.f + *eps_p;
    float v;
    if (t < 128) {
        float acc = 0.f;
        for (int j = 0; j < 256; j++) acc += w1row[j] * lin_w[j * 128 + t];
        v = acc + onepe * (w1row[t] + w1row[t + 128]);
    } else {
        int m = t - 128;
        v = w1row[m] + w1row[t];
    }
    wc[c * 256 + t] = (bf16_t)v;
    red[t] = w1row[t] * lin_b[t];
    __syncthreads();
    for (int off = 128; off > 0; off >>= 1) {
        if (t < off) red[t] += red[t + off];
        __syncthreads();
    }
    if (t == 0) bcomb[c] = red[0];
}

// ---------------- edge-index dtype detection ----------------
__global__ void detect_k(const int* __restrict__ ei, int* __restrict__ flag) {
    int v = ei[2 * threadIdx.x + 1];
    if (v != 0) atomicOr(flag, 1);   // 1 => int32 layout
}

// ---------------- bucket sort of edges (bucket = dst >> 7, 128 nodes/bucket) ----------------
#define CHUNK 8192

__global__ __launch_bounds__(256) void bhist_k(const void* __restrict__ ei, const int* __restrict__ flag,
                                               int E, int* __restrict__ bcnt) {
    __shared__ int cnt[1024];
    int t = threadIdx.x;
    for (int b = t; b < 1024; b += 256) cnt[b] = 0;
    __syncthreads();
    int base = blockIdx.x * CHUNK;
    int i32 = *flag;
#pragma unroll 4
    for (int i = 0; i < CHUNK / 256; i++) {
        int e = base + t + 256 * i;
        if (e < E) {
            int dst = i32 ? ((const int*)ei)[e] : (int)((const long long*)ei)[e];
            atomicAdd(&cnt[dst >> 7], 1);
        }
    }
    __syncthreads();
    for (int b = t; b < 1024; b += 256)
        if (cnt[b]) atomicAdd(&bcnt[b], cnt[b]);
}

__global__ __launch_bounds__(1024) void bscan_k(const int* __restrict__ bcnt, int* __restrict__ boffs,
                                                int* __restrict__ gcur, int* __restrict__ offs,
                                                int NBK, int N, int E) {
    __shared__ int lds[1024];
    int t = threadIdx.x;
    int v = (t < NBK) ? bcnt[t] : 0;
    lds[t] = v;
    __syncthreads();
    for (int off = 1; off < 1024; off <<= 1) {
        int add = (t >= off) ? lds[t - off] : 0;
        __syncthreads();
        lds[t] += add;
        __syncthreads();
    }
    if (t < NBK) {
        int excl = lds[t] - v;
        boffs[t] = excl;
        gcur[t] = excl;
    }
    if (t == 0) { boffs[NBK] = E; offs[N] = E; }
}

// per-block multisplit: LDS hist -> LDS scan -> LDS placement -> coalesced flush
__global__ __launch_bounds__(256) void binfill_k(const void* __restrict__ ei, const int* __restrict__ flag,
                                                 int E, int NBK, int* __restrict__ gcur,
                                                 unsigned* __restrict__ pairs) {
    __shared__ int cnt[1024];
    __shared__ int pref[1024];
    __shared__ int cur[1024];
    __shared__ int gbase[1024];
    __shared__ int red[256];
    __shared__ unsigned slot[CHUNK];
    int t = threadIdx.x;
    int base = blockIdx.x * CHUNK;
    int chunk_n = E - base; if (chunk_n > CHUNK) chunk_n = CHUNK;
    int i32 = *flag;
    for (int b = t; b < 1024; b += 256) cnt[b] = 0;
    __syncthreads();
    // pass 1: hist
#pragma unroll 4
    for (int i = 0; i < CHUNK / 256; i++) {
        int e = base + t + 256 * i;
        if (e < E) {
            int dst = i32 ? ((const int*)ei)[e] : (int)((const long long*)ei)[e];
            atomicAdd(&cnt[dst >> 7], 1);
        }
    }
    __syncthreads();
    // scan cnt[1024] with 256 threads (4 per thread)
    int t4 = t * 4;
    int c0 = cnt[t4], c1 = cnt[t4 + 1], c2 = cnt[t4 + 2], c3 = cnt[t4 + 3];
    int s = c0 + c1 + c2 + c3;
    red[t] = s;
    __syncthreads();
    for (int off = 1; off < 256; off <<= 1) {
        int add = (t >= off) ? red[t - off] : 0;
        __syncthreads();
        red[t] += add;
        __syncthreads();
    }
    int run = red[t] - s;
    pref[t4] = run; cur[t4] = run; run += c0;
    pref[t4 + 1] = run; cur[t4 + 1] = run; run += c1;
    pref[t4 + 2] = run; cur[t4 + 2] = run; run += c2;
    pref[t4 + 3] = run; cur[t4 + 3] = run;
    __syncthreads();
    // pass 2: place into LDS slots
#pragma unroll 4
    for (int i = 0; i < CHUNK / 256; i++) {
        int e = base + t + 256 * i;
        if (e < E) {
            int dst, src;
            if (i32) { dst = ((const int*)ei)[e]; src = ((const int*)ei)[E + e]; }
            else     { dst = (int)((const long long*)ei)[e]; src = (int)((const long long*)ei)[E + e]; }
            int b = dst >> 7;
            int p = atomicAdd(&cur[b], 1);
            slot[p] = ((unsigned)(dst & 127) << 20) | (unsigned)src;
        }
    }
    __syncthreads();
    // per-bucket global base
    for (int b = t; b < 1024; b += 256) {
        int c = (b + 1 < 1024) ? (pref[b + 1] - pref[b]) : (chunk_n - pref[b]);
        if (b < NBK && c > 0) gbase[b] = atomicAdd(&gcur[b], c);
    }
    __syncthreads();
    // coalesced flush: consecutive lanes -> consecutive slots
    for (int i = t; i < chunk_n; i += 256) {
        int lo = 0, hi = NBK - 1;
        while (lo < hi) {
            int mid = (lo + hi + 1) >> 1;
            if (pref[mid] <= i) lo = mid; else hi = mid - 1;
        }
        pairs[gbase[lo] + (i - pref[lo])] = slot[i];
    }
}

// level-2 counting sort: one block per bucket -> per-node CSR + offs
__global__ __launch_bounds__(256) void bsort2_k(const unsigned* __restrict__ pairs,
                                                const int* __restrict__ boffs,
                                                int* __restrict__ offs,
                                                int* __restrict__ csr, int N) {
    __shared__ int cnt[128], pref[128], cur[128];
    int t = threadIdx.x;
    int b = blockIdx.x;
    int s = boffs[b], e = boffs[b + 1];
    if (t < 128) cnt[t] = 0;
    __syncthreads();
    for (int i = s + t; i < e; i += 256)
        atomicAdd(&cnt[pairs[i] >> 20], 1);
    __syncthreads();
    if (t < 128) pref[t] = cnt[t];
    __syncthreads();
    for (int off = 1; off < 128; off <<= 1) {
        int v = 0;
        if (t < 128 && t >= off) v = pref[t - off];
        __syncthreads();
        if (t < 128) pref[t] += v;
        __syncthreads();
    }
    if (t < 128) {
        int ex = pref[t] - cnt[t];      // exclusive prefix
        cur[t] = ex;
        int node = b * 128 + t;
        if (node < N) offs[node] = s + ex;
    }
    __syncthreads();
    for (int i = s + t; i < e; i += 256) {
        unsigned u = pairs[i];
        int dl = (int)(u >> 20);
        int p = atomicAdd(&cur[dl], 1);
        csr[s + p] = (int)(u & 0xFFFFFu);
    }
}

// one wave per node; 4 neighbor rows in flight, 16 lanes x 16B (bf16x8) per row
__global__ __launch_bounds__(256) void gather_k(bf16_t* __restrict__ ha, const int* __restrict__ offs,
                                                const int* __restrict__ csr, int N) {
    int w = (blockIdx.x * 256 + threadIdx.x) >> 6;
    if (w >= N) return;
    int lane = threadIdx.x & 63;
    int g = lane >> 4, l15 = lane & 15;
    int s = offs[w], e = offs[w + 1];
    float acc[8] = {0.f, 0.f, 0.f, 0.f, 0.f, 0.f, 0.f, 0.f};
    for (int i = s + g; i < e; i += 4) {
        int src = csr[i];
        bf16x8 v = *(const bf16x8*)(ha + (size_t)src * 256 + l15 * 8);
#pragma unroll
        for (int j = 0; j < 8; j++) acc[j] += (float)v[j];
    }
#pragma unroll
    for (int j = 0; j < 8; j++) {
        acc[j] += __shfl_xor(acc[j], 16);
        acc[j] += __shfl_xor(acc[j], 32);
    }
    if (g == 0) {
        bf16x8 o;
#pragma unroll
        for (int j = 0; j < 8; j++) o[j] = (bf16_t)acc[j];
        *(bf16x8*)(ha + (size_t)w * 256 + 128 + l15 * 8) = o;
    }
}

// ---------------- PERSISTENT whole-W-in-LDS K=256 MFMA GEMM (spill-fixed) ----------------
// Grid = 256 (1 block/CU). W staged to LDS once per block (520B padded col
// stride: both the stage-write and the b128 fragment-read are exactly
// 8-accesses/bank — optimal). Main loop has ZERO barriers: loadA(t+1) issues
// while compute(t) runs; the compiler emits counted vmcnt(N) waits (never a
// drain) because no __syncthreads intervenes. KEY FIX vs R9: __launch_bounds__
// (512,1) gives the 256-VGPR budget the ping-pong A registers (128) + acc (64)
// need — R9's (512,2) capped at 128 VGPR and spilled to scratch (the +60MB
// WRITE / +48MB FETCH in its counters). Epilogue: direct scatter stores
// (proven clean 51.5MB in R3/R10); stats accumulate in registers across tiles,
// one atomicAdd per column per wave at kernel end.
// mfma_f32_16x16x32_bf16 (m89): A lane A[l&15][(l>>4)*8+i]; B lane B[k][l&15];
// D reg i <-> out[row=(l>>4)*4+i][col=l&15].
#define GEMM_GRID 256

template<int NCOL, bool BNIN, bool STATS, bool FINAL, bool BIAS>
__global__ __launch_bounds__(512, 1) void gemm_p(
    const bf16_t* __restrict__ A, const bf16_t* __restrict__ W,
    const float2* __restrict__ scsh2,
    float* __restrict__ sums, float* __restrict__ sqs,
    const float* __restrict__ bias,
    bf16_t* __restrict__ Obf, float* __restrict__ Of, int N, int ntiles)
{
    constexpr int NT = 512;
    constexpr int WSTR = 520;                 // padded LDS col stride (bytes)
    constexpr int COLG = NCOL / 128;          // col wave-groups (2 or 1)
    constexpr int RG = 8 / COLG;              // row wave-groups (4 or 8)
    constexpr int TR = RG * 32;               // rows per tile (128 or 256)
    __shared__ __align__(16) char smemW[NCOL * WSTR];
    __shared__ float2 ssl[BNIN ? 256 : 1];

    const int tid = threadIdx.x;
    const int lane = tid & 63, wid = tid >> 6;
    const int l15 = lane & 15, l4 = lane >> 4;
    const int wr = wid % RG, wc = wid / RG;
    const int cb = wc * 128;

    if constexpr (BNIN) { if (tid < 256) ssl[tid] = scsh2[tid]; }

    // stage whole W -> LDS (once per block); both sides 8-accesses/bank
#pragma unroll
    for (int it = 0; it < NCOL * 512 / (NT * 16); it++) {
        int g = (it * NT + tid) * 16;
        bf16x8 v = *(const bf16x8*)((const char*)W + g);
        int col = g >> 9, koff = g & 511;
        *(bf16x8*)(smemW + col * WSTR + koff) = v;
    }

    float bbv[8];
    if constexpr (BIAS || FINAL) {
#pragma unroll
        for (int ot = 0; ot < 8; ot++) bbv[ot] = bias[cb + ot * 16 + l15];
    }
    float sA[8], qA[8];
    if constexpr (STATS) {
#pragma unroll
        for (int ot = 0; ot < 8; ot++) { sA[ot] = 0.f; qA[ot] = 0.f; }
    }

    f32x4 acc0[8], acc1[8];
    bf16x8 aA0[8], aA1[8], aB0[8], aB1[8];

    auto loadA = [&](int t, bf16x8 (&r0)[8], bf16x8 (&r1)[8]) {
        int rows0 = t * TR + wr * 32;
        int ra0 = rows0 + l15;      if (ra0 > N - 1) ra0 = N - 1;
        int ra1 = rows0 + 16 + l15; if (ra1 > N - 1) ra1 = N - 1;
#pragma unroll
        for (int c = 0; c < 8; c++) {
            r0[c] = *(const bf16x8*)(A + (size_t)ra0 * 256 + c * 32 + l4 * 8);
            r1[c] = *(const bf16x8*)(A + (size_t)ra1 * 256 + c * 32 + l4 * 8);
        }
    };

    auto compute = [&](bf16x8 (&r0)[8], bf16x8 (&r1)[8]) {
#pragma unroll
        for (int i = 0; i < 8; i++) { acc0[i] = f32x4{0.f,0.f,0.f,0.f}; acc1[i] = f32x4{0.f,0.f,0.f,0.f}; }
#pragma unroll
        for (int c = 0; c < 8; c++) {
            bf16x8 ca0 = r0[c], ca1 = r1[c];
            if constexpr (BNIN) {
                const int k0 = c * 32 + l4 * 8;
                bf16x8 t0, t1;
#pragma unroll
                for (int i = 0; i < 8; i++) {
                    float2 ss = ssl[k0 + i];
                    float f0 = (float)ca0[i] * ss.x + ss.y; f0 = fmaxf(f0, 0.f);
                    float f1 = (float)ca1[i] * ss.x + ss.y; f1 = fmaxf(f1, 0.f);
                    t0[i] = (bf16_t)f0; t1[i] = (bf16_t)f1;
                }
                ca0 = t0; ca1 = t1;
            }
#pragma unroll
            for (int ot = 0; ot < 8; ot++) {
                const bf16x8 b = *(const bf16x8*)(smemW + (cb + ot * 16 + l15) * WSTR + c * 64 + l4 * 16);
                acc0[ot] = __builtin_amdgcn_mfma_f32_16x16x32_bf16(ca0, b, acc0[ot], 0, 0, 0);
                acc1[ot] = __builtin_amdgcn_mfma_f32_16x16x32_bf16(ca1, b, acc1[ot], 0, 0, 0);
            }
        }
    };

    auto epilogue = [&](int t) {
        const int rows0 = t * TR + wr * 32;
        const int rb0 = rows0 + l4 * 4, rb1 = rows0 + 16 + l4 * 4;
#pragma unroll
        for (int ot = 0; ot < 8; ot++) {
            int colw = cb + ot * 16 + l15;
#pragma unroll
            for (int h = 0; h < 2; h++) {
                int rb = h ? rb1 : rb0;
                f32x4 av = h ? acc1[ot] : acc0[ot];
#pragma unroll
                for (int i = 0; i < 4; i++) {
                    int r = rb + i;
                    if constexpr (FINAL) {
                        if (r < N) Of[(size_t)r * NCOL + colw] = av[i] + bbv[ot];
                    } else {
                        float v = av[i];
                        if constexpr (BIAS) v += bbv[ot];
                        bf16_t hv = (bf16_t)v;
                        if (r < N) Obf[(size_t)r * 256 + colw] = hv;
                        if constexpr (STATS) {
                            float vv = (r < N) ? (float)hv : 0.f;
                            sA[ot] += vv; qA[ot] += vv * vv;
                        }
                    }
                }
            }
        }
    };

    int t = blockIdx.x;
    if (t < ntiles) loadA(t, aA0, aA1);
    __syncthreads();   // W + ssl staged; the ONLY barrier

    while (t < ntiles) {
        int tn = t + GEMM_GRID;
        if (tn < ntiles) loadA(tn, aB0, aB1);
        compute(aA0, aA1);
        epilogue(t);
        t = tn;
        if (t >= ntiles) break;
        tn = t + GEMM_GRID;
        if (tn < ntiles) loadA(tn, aA0, aA1);
        compute(aB0, aB1);
        epilogue(t);
        t = tn;
    }

    if constexpr (STATS) {
#pragma unroll
        for (int ot = 0; ot < 8; ot++) {
            float s = sA[ot], q = qA[ot];
            s += __shfl_xor(s, 16); s += __shfl_xor(s, 32);
            q += __shfl_xor(q, 16); q += __shfl_xor(q, 32);
            if (lane < 16) {
                atomicAdd(&sums[cb + ot * 16 + l15], s);
                atomicAdd(&sqs[cb + ot * 16 + l15], q);
            }
        }
    }
}

__global__ void finalize_k(const float* __restrict__ sum, const float* __restrict__ sq,
                           const float* __restrict__ g, const float* __restrict__ b,
                           float2* __restrict__ scsh2, float invN) {
    int t = threadIdx.x;
    float mean = sum[t] * invN;
    float var = sq[t] * invN - mean * mean;
    float s = g[t] * rsqrtf(var + 1e-5f);
    scsh2[t] = make_float2(s, b[t] - mean * s);
}

extern "C" void kernel_launch(void* const* d_in, const int* in_sizes, int n_in,
                              void* d_out, int out_size, void* d_ws, size_t ws_size,
                              hipStream_t stream)
{
    const int N = in_sizes[0] / 128;
    const int E = in_sizes[1] / 2;
    const float* x     = (const float*)d_in[0];
    const void*  ei    = d_in[1];
    const float* lin_w = (const float*)d_in[2];
    const float* lin_b = (const float*)d_in[3];
    const float* eps   = (const float*)d_in[4];
    const float* w1    = (const float*)d_in[5];
    const float* g1    = (const float*)d_in[6];
    const float* b1    = (const float*)d_in[7];
    const float* w2    = (const float*)d_in[8];
    const float* g2    = (const float*)d_in[9];
    const float* b2    = (const float*)d_in[10];
    const float* w3    = (const float*)d_in[11];
    const float* b3    = (const float*)d_in[12];
    float* out = (float*)d_out;

    char* ws = (char*)d_ws;
    size_t o = 0;
    auto alloc = [&](size_t bytes) -> char* {
        char* p = ws + o;
        o = (o + bytes + 255) & ~(size_t)255;
        return p;
    };
    bf16_t*   ha    = (bf16_t*)alloc((size_t)N * 256 * 2);  // [x | agg], later t2
    bf16_t*   hb    = (bf16_t*)alloc((size_t)N * 256 * 2);  // t1
    bf16_t*   wcb   = (bf16_t*)alloc((size_t)256 * 256 * 2);
    bf16_t*   w2b   = (bf16_t*)alloc((size_t)256 * 256 * 2);
    bf16_t*   w3b   = (bf16_t*)alloc((size_t)128 * 256 * 2);
    float*    bcomb = (float*)alloc(256 * 4);
    float*    stats = (float*)alloc(4 * 256 * 4);   // sum1, sq1, sum2, sq2
    float2*   scsh1 = (float2*)alloc(256 * 8);
    float2*   scsh2 = (float2*)alloc(256 * 8);
    int*      bcnt  = (int*)alloc(1024 * 4);
    int*      boffs = (int*)alloc(1025 * 4);
    int*      gcur  = (int*)alloc(1024 * 4);
    int*      offs  = (int*)alloc((size_t)(N + 1) * 4);
    unsigned* pairs = (unsigned*)alloc((size_t)E * 4);
    int*      csr   = (int*)alloc((size_t)E * 4);
    int*      flag  = (int*)alloc(4);

    const int NBK = (N + 127) >> 7;

    hipMemsetAsync(bcnt, 0, 1024 * 4, stream);
    hipMemsetAsync(stats, 0, 4 * 256 * 4, stream);
    hipMemsetAsync(flag, 0, 4, stream);

    // conversions / weight prep
    int nx8 = N * 16;
    conv_x_k<<<(nx8 + 255) / 256, 256, 0, stream>>>(x, ha, nx8);
    wcomb_k<<<256, 256, 0, stream>>>(w1, lin_w, lin_b, eps, wcb, bcomb);
    conv_k<<<32, 256, 0, stream>>>(w2, w2b, 8192);
    conv_k<<<16, 256, 0, stream>>>(w3, w3b, 4096);

    // two-level bucket sort of edges -> per-node CSR (all writes coalesced)
    const int nch = (E + CHUNK - 1) / CHUNK;
    detect_k<<<1, 256, 0, stream>>>((const int*)ei, flag);
    bhist_k<<<nch, 256, 0, stream>>>(ei, flag, E, bcnt);
    bscan_k<<<1, 1024, 0, stream>>>(bcnt, boffs, gcur, offs, NBK, N, E);
    binfill_k<<<nch, 256, 0, stream>>>(ei, flag, E, NBK, gcur, pairs);
    bsort2_k<<<NBK, 256, 0, stream>>>(pairs, boffs, offs, csr, N);
    gather_k<<<(N + 3) / 4, 256, 0, stream>>>(ha, offs, csr, N);

    const int nt128 = (N + 127) / 128;
    const int nt256 = (N + 255) / 256;
    // t1 = [x|agg] @ Wc^T + bcomb (+ BN1 stats)
    gemm_p<256, false, true, false, true><<<GEMM_GRID, 512, 0, stream>>>(
        ha, wcb, nullptr, stats + 0, stats + 256, bcomb, hb, nullptr, N, nt128);
    finalize_k<<<1, 256, 0, stream>>>(stats + 0, stats + 256, g1, b1, scsh1, 1.f / (float)N);
    // t2 = relu(BN1(t1))@w2^T (+ BN2 stats)
    gemm_p<256, true, true, false, false><<<GEMM_GRID, 512, 0, stream>>>(
        hb, w2b, scsh1, stats + 512, stats + 768, nullptr, ha, nullptr, N, nt128);
    finalize_k<<<1, 256, 0, stream>>>(stats + 512, stats + 768, g2, b2, scsh2, 1.f / (float)N);
    // out = relu(BN2(t2))@w3^T + b3
    gemm_p<128, true, false, true, true><<<GEMM_GRID, 512, 0, stream>>>(
        ha, w3b, scsh2, nullptr, nullptr, b3, nullptr, out, N, nt256);
}

// Round 12
// 309.347 us; speedup vs baseline: 1.1572x; 1.1572x over previous
//
#include <hip/hip_runtime.h>
#include <cstdint>
#include <cstddef>

typedef __bf16 bf16_t;
typedef __bf16 bf16x8 __attribute__((ext_vector_type(8)));
typedef float f32x4 __attribute__((ext_vector_type(4)));

#define GLOBAL_AS __attribute__((address_space(1)))
#define LDS_AS    __attribute__((address_space(3)))

__device__ __forceinline__ void glds16(const void* g, void* l) {
    __builtin_amdgcn_global_load_lds((const GLOBAL_AS void*)g, (LDS_AS void*)l, 16, 0, 0);
}

// ---------------- conversions ----------------
__global__ void conv_k(const float* __restrict__ in, bf16_t* __restrict__ out, int n8) {
    int id = blockIdx.x * 256 + threadIdx.x;
    if (id >= n8) return;
    const float4* p = (const float4*)in;
    float4 a = p[2 * id], b = p[2 * id + 1];
    bf16x8 o;
    o[0] = (bf16_t)a.x; o[1] = (bf16_t)a.y; o[2] = (bf16_t)a.z; o[3] = (bf16_t)a.w;
    o[4] = (bf16_t)b.x; o[5] = (bf16_t)b.y; o[6] = (bf16_t)b.z; o[7] = (bf16_t)b.w;
    *(bf16x8*)(out + (size_t)id * 8) = o;
}

// x fp32 -> cols 0..127 of interleaved ha[N][256]
__global__ void conv_x_k(const float* __restrict__ in, bf16_t* __restrict__ ha, int n8) {
    int id = blockIdx.x * 256 + threadIdx.x;
    if (id >= n8) return;
    const float4* p = (const float4*)in;
    float4 a = p[2 * id], b = p[2 * id + 1];
    bf16x8 o;
    o[0] = (bf16_t)a.x; o[1] = (bf16_t)a.y; o[2] = (bf16_t)a.z; o[3] = (bf16_t)a.w;
    o[4] = (bf16_t)b.x; o[5] = (bf16_t)b.y; o[6] = (bf16_t)b.z; o[7] = (bf16_t)b.w;
    int row = id >> 4, ch = id & 15;
    *(bf16x8*)(ha + (size_t)row * 256 + ch * 8) = o;
}

// ---------------- merged weight: Wc = w1 @ W0, bcomb = w1 @ lin_b ----------------
__global__ void wcomb_k(const float* __restrict__ w1, const float* __restrict__ lin_w,
                        const float* __restrict__ lin_b, const float* __restrict__ eps_p,
                        bf16_t* __restrict__ wc, float* __restrict__ bcomb) {
    __shared__ float red[256];
    int c = blockIdx.x, t = threadIdx.x;
    const float* w1row = w1 + c * 256;
    float onepe = 1.f + *eps_p;
    float v;
    if (t < 128) {
        float acc = 0.f;
        for (int j = 0; j < 256; j++) acc += w1row[j] * lin_w[j * 128 + t];
        v = acc + onepe * (w1row[t] + w1row[t + 128]);
    } else {
        int m = t - 128;
        v = w1row[m] + w1row[t];
    }
    wc[c * 256 + t] = (bf16_t)v;
    red[t] = w1row[t] * lin_b[t];
    __syncthreads();
    for (int off = 128; off > 0; off >>= 1) {
        if (t < off) red[t] += red[t + off];
        __syncthreads();
    }
    if (t == 0) bcomb[c] = red[0];
}

// ---------------- edge-index dtype detection ----------------
__global__ void detect_k(const int* __restrict__ ei, int* __restrict__ flag) {
    int v = ei[2 * threadIdx.x + 1];
    if (v != 0) atomicOr(flag, 1);   // 1 => int32 layout
}

// ---------------- bucket sort of edges (bucket = dst >> 7, 128 nodes/bucket) ----------------
#define CHUNK 8192

__global__ __launch_bounds__(256) void bhist_k(const void* __restrict__ ei, const int* __restrict__ flag,
                                               int E, int* __restrict__ bcnt) {
    __shared__ int cnt[1024];
    int t = threadIdx.x;
    for (int b = t; b < 1024; b += 256) cnt[b] = 0;
    __syncthreads();
    int base = blockIdx.x * CHUNK;
    int i32 = *flag;
#pragma unroll 4
    for (int i = 0; i < CHUNK / 256; i++) {
        int e = base + t + 256 * i;
        if (e < E) {
            int dst = i32 ? ((const int*)ei)[e] : (int)((const long long*)ei)[e];
            atomicAdd(&cnt[dst >> 7], 1);
        }
    }
    __syncthreads();
    for (int b = t; b < 1024; b += 256)
        if (cnt[b]) atomicAdd(&bcnt[b], cnt[b]);
}

__global__ __launch_bounds__(1024) void bscan_k(const int* __restrict__ bcnt, int* __restrict__ boffs,
                                                int* __restrict__ gcur, int* __restrict__ offs,
                                                int NBK, int N, int E) {
    __shared__ int lds[1024];
    int t = threadIdx.x;
    int v = (t < NBK) ? bcnt[t] : 0;
    lds[t] = v;
    __syncthreads();
    for (int off = 1; off < 1024; off <<= 1) {
        int add = (t >= off) ? lds[t - off] : 0;
        __syncthreads();
        lds[t] += add;
        __syncthreads();
    }
    if (t < NBK) {
        int excl = lds[t] - v;
        boffs[t] = excl;
        gcur[t] = excl;
    }
    if (t == 0) { boffs[NBK] = E; offs[N] = E; }
}

// per-block multisplit: LDS hist -> LDS scan -> LDS placement -> coalesced flush
__global__ __launch_bounds__(256) void binfill_k(const void* __restrict__ ei, const int* __restrict__ flag,
                                                 int E, int NBK, int* __restrict__ gcur,
                                                 unsigned* __restrict__ pairs) {
    __shared__ int cnt[1024];
    __shared__ int pref[1024];
    __shared__ int cur[1024];
    __shared__ int gbase[1024];
    __shared__ int red[256];
    __shared__ unsigned slot[CHUNK];
    int t = threadIdx.x;
    int base = blockIdx.x * CHUNK;
    int chunk_n = E - base; if (chunk_n > CHUNK) chunk_n = CHUNK;
    int i32 = *flag;
    for (int b = t; b < 1024; b += 256) cnt[b] = 0;
    __syncthreads();
    // pass 1: hist
#pragma unroll 4
    for (int i = 0; i < CHUNK / 256; i++) {
        int e = base + t + 256 * i;
        if (e < E) {
            int dst = i32 ? ((const int*)ei)[e] : (int)((const long long*)ei)[e];
            atomicAdd(&cnt[dst >> 7], 1);
        }
    }
    __syncthreads();
    // scan cnt[1024] with 256 threads (4 per thread)
    int t4 = t * 4;
    int c0 = cnt[t4], c1 = cnt[t4 + 1], c2 = cnt[t4 + 2], c3 = cnt[t4 + 3];
    int s = c0 + c1 + c2 + c3;
    red[t] = s;
    __syncthreads();
    for (int off = 1; off < 256; off <<= 1) {
        int add = (t >= off) ? red[t - off] : 0;
        __syncthreads();
        red[t] += add;
        __syncthreads();
    }
    int run = red[t] - s;
    pref[t4] = run; cur[t4] = run; run += c0;
    pref[t4 + 1] = run; cur[t4 + 1] = run; run += c1;
    pref[t4 + 2] = run; cur[t4 + 2] = run; run += c2;
    pref[t4 + 3] = run; cur[t4 + 3] = run;
    __syncthreads();
    // pass 2: place into LDS slots
#pragma unroll 4
    for (int i = 0; i < CHUNK / 256; i++) {
        int e = base + t + 256 * i;
        if (e < E) {
            int dst, src;
            if (i32) { dst = ((const int*)ei)[e]; src = ((const int*)ei)[E + e]; }
            else     { dst = (int)((const long long*)ei)[e]; src = (int)((const long long*)ei)[E + e]; }
            int b = dst >> 7;
            int p = atomicAdd(&cur[b], 1);
            slot[p] = ((unsigned)(dst & 127) << 20) | (unsigned)src;
        }
    }
    __syncthreads();
    // per-bucket global base
    for (int b = t; b < 1024; b += 256) {
        int c = (b + 1 < 1024) ? (pref[b + 1] - pref[b]) : (chunk_n - pref[b]);
        if (b < NBK && c > 0) gbase[b] = atomicAdd(&gcur[b], c);
    }
    __syncthreads();
    // coalesced flush: consecutive lanes -> consecutive slots
    for (int i = t; i < chunk_n; i += 256) {
        int lo = 0, hi = NBK - 1;
        while (lo < hi) {
            int mid = (lo + hi + 1) >> 1;
            if (pref[mid] <= i) lo = mid; else hi = mid - 1;
        }
        pairs[gbase[lo] + (i - pref[lo])] = slot[i];
    }
}

// level-2 counting sort: one block per bucket -> per-node CSR + offs
__global__ __launch_bounds__(256) void bsort2_k(const unsigned* __restrict__ pairs,
                                                const int* __restrict__ boffs,
                                                int* __restrict__ offs,
                                                int* __restrict__ csr, int N) {
    __shared__ int cnt[128], pref[128], cur[128];
    int t = threadIdx.x;
    int b = blockIdx.x;
    int s = boffs[b], e = boffs[b + 1];
    if (t < 128) cnt[t] = 0;
    __syncthreads();
    for (int i = s + t; i < e; i += 256)
        atomicAdd(&cnt[pairs[i] >> 20], 1);
    __syncthreads();
    if (t < 128) pref[t] = cnt[t];
    __syncthreads();
    for (int off = 1; off < 128; off <<= 1) {
        int v = 0;
        if (t < 128 && t >= off) v = pref[t - off];
        __syncthreads();
        if (t < 128) pref[t] += v;
        __syncthreads();
    }
    if (t < 128) {
        int ex = pref[t] - cnt[t];      // exclusive prefix
        cur[t] = ex;
        int node = b * 128 + t;
        if (node < N) offs[node] = s + ex;
    }
    __syncthreads();
    for (int i = s + t; i < e; i += 256) {
        unsigned u = pairs[i];
        int dl = (int)(u >> 20);
        int p = atomicAdd(&cur[dl], 1);
        csr[s + p] = (int)(u & 0xFFFFFu);
    }
}

// one wave per node; 4 neighbor rows in flight, 16 lanes x 16B (bf16x8) per row
__global__ __launch_bounds__(256) void gather_k(bf16_t* __restrict__ ha, const int* __restrict__ offs,
                                                const int* __restrict__ csr, int N) {
    int w = (blockIdx.x * 256 + threadIdx.x) >> 6;
    if (w >= N) return;
    int lane = threadIdx.x & 63;
    int g = lane >> 4, l15 = lane & 15;
    int s = offs[w], e = offs[w + 1];
    float acc[8] = {0.f, 0.f, 0.f, 0.f, 0.f, 0.f, 0.f, 0.f};
    for (int i = s + g; i < e; i += 4) {
        int src = csr[i];
        bf16x8 v = *(const bf16x8*)(ha + (size_t)src * 256 + l15 * 8);
#pragma unroll
        for (int j = 0; j < 8; j++) acc[j] += (float)v[j];
    }
#pragma unroll
    for (int j = 0; j < 8; j++) {
        acc[j] += __shfl_xor(acc[j], 16);
        acc[j] += __shfl_xor(acc[j], 32);
    }
    if (g == 0) {
        bf16x8 o;
#pragma unroll
        for (int j = 0; j < 8; j++) o[j] = (bf16_t)acc[j];
        *(bf16x8*)(ha + (size_t)w * 256 + 128 + l15 * 8) = o;
    }
}

// ---------------- W-resident + A-LDS-tiled K=256 MFMA GEMM ----------------
// Block: 512 threads = 8 waves (2 rowg x 4 colg). One 64KB W column-half is
// staged into LDS ONCE per block (glds, XOR-swizzled source per R10's proven
// 0-conflict pattern), then the block grid-strides over 64-row A-tiles with a
// double-buffered A stage (32KB/buf, also glds + XOR swizzle: row-major 512B
// stride, koff^=(row&7)<<4 -> b128 frag reads are 2 lanes/bank = free).
// Per barrier: 256 MFMA + a full 64x128 epilogue (~1500cy) hides the ~900cy
// A-glds latency; W prologue amortizes over ~6 tiles. Registers stay tiny
// (acc 16 + frags ~12 + misc ~ 80 VGPR): no spill possible (the R9/R11
// failure). Stats accumulate in 2 regs/lane across tiles; 1 atomic/col/block.
// mfma_f32_16x16x32_bf16 (m89): A lane A[l&15][(l>>4)*8+i]; B lane B[k][l&15];
// D reg i <-> out[row=(l>>4)*4+i][col=l&15].
template<int NHALF, bool BNIN, bool STATS, bool FINAL, bool BIAS>
__global__ __launch_bounds__(512, 1) void gemm_w(
    const bf16_t* __restrict__ A, const bf16_t* __restrict__ W,
    const float2* __restrict__ scsh2,
    float* __restrict__ sums, float* __restrict__ sqs,
    const float* __restrict__ bias,
    bf16_t* __restrict__ Obf, float* __restrict__ Of, int N, int ntiles)
{
    constexpr int NCOLTOT = NHALF * 128;
    __shared__ __align__(16) char smemW[65536];      // 128 cols x 512B
    __shared__ __align__(16) char smemA[2][32768];   // 2 x (64 rows x 512B)
    __shared__ float2 ssl[BNIN ? 256 : 1];

    const int tid = threadIdx.x;
    const int lane = tid & 63, wid = tid >> 6;
    const int l15 = lane & 15, l4 = lane >> 4;
    const int rowg = wid & 1, colg = wid >> 1;       // 2 rowg x 4 colg
    const int colh = blockIdx.x % NHALF;
    const int rb = blockIdx.x / NHALF;               // row-stride id in [0,256)

    if constexpr (BNIN) { if (tid < 256) ssl[tid] = scsh2[tid]; }

    // stage the W column-half (64KB) once: swizzled global source, linear LDS
#pragma unroll
    for (int it = 0; it < 8; it++) {
        int d = (it * 512 + tid) * 16;
        int col = d >> 9, koff = d & 511;
        int ksw = koff ^ (((col >> 1) & 3) << 4);
        glds16((const char*)W + (size_t)(colh * 128 + col) * 512 + ksw, smemW + d);
    }

    auto stageA = [&](int buf, int t) {
        size_t rowbase = (size_t)t * 64;
#pragma unroll
        for (int it = 0; it < 4; it++) {
            int d = (it * 512 + tid) * 16;
            int row = d >> 9, koff = d & 511;
            int ksw = koff ^ ((row & 7) << 4);
            glds16((const char*)A + (rowbase + row) * 512 + ksw, smemA[buf] + d);
        }
    };

    float bbv[2];
    if constexpr (BIAS || FINAL) {
#pragma unroll
        for (int cf = 0; cf < 2; cf++)
            bbv[cf] = bias[colh * 128 + colg * 32 + cf * 16 + l15];
    }
    float sA[2], qA[2];
    if constexpr (STATS) { sA[0] = sA[1] = qA[0] = qA[1] = 0.f; }

    int t = rb;
    if (t < ntiles) stageA(0, t);
    __syncthreads();

    int buf = 0;
    while (t < ntiles) {
        int tn = t + 256;
        if (tn < ntiles) stageA(buf ^ 1, tn);

        // compute 64x128 tile: wave = 32 rows (rowg) x 32 cols (colg)
        f32x4 acc[2][2];
#pragma unroll
        for (int i = 0; i < 2; i++) { acc[i][0] = f32x4{0.f,0.f,0.f,0.f}; acc[i][1] = f32x4{0.f,0.f,0.f,0.f}; }
#pragma unroll
        for (int c = 0; c < 8; c++) {
            const int koff = c * 64 + l4 * 16;
            bf16x8 a[2];
#pragma unroll
            for (int fr = 0; fr < 2; fr++) {
                int row = rowg * 32 + fr * 16 + l15;
                a[fr] = *(const bf16x8*)(smemA[buf] + row * 512 + (koff ^ ((row & 7) << 4)));
            }
            if constexpr (BNIN) {
                const int k0 = c * 32 + l4 * 8;
#pragma unroll
                for (int fr = 0; fr < 2; fr++) {
                    bf16x8 tt;
#pragma unroll
                    for (int i = 0; i < 8; i++) {
                        float2 ss = ssl[k0 + i];
                        float f = (float)a[fr][i] * ss.x + ss.y;
                        tt[i] = (bf16_t)fmaxf(f, 0.f);
                    }
                    a[fr] = tt;
                }
            }
#pragma unroll
            for (int cf = 0; cf < 2; cf++) {
                int col = colg * 32 + cf * 16 + l15;
                const bf16x8 b = *(const bf16x8*)(smemW + col * 512 + (koff ^ (((col >> 1) & 3) << 4)));
                acc[0][cf] = __builtin_amdgcn_mfma_f32_16x16x32_bf16(a[0], b, acc[0][cf], 0, 0, 0);
                acc[1][cf] = __builtin_amdgcn_mfma_f32_16x16x32_bf16(a[1], b, acc[1][cf], 0, 0, 0);
            }
        }

        // epilogue: direct scatter stores (clean per R3/R10) + register stats
        const int rows0 = t * 64 + rowg * 32;
#pragma unroll
        for (int fr = 0; fr < 2; fr++) {
            int rb0 = rows0 + fr * 16 + l4 * 4;
#pragma unroll
            for (int cf = 0; cf < 2; cf++) {
                int colw = colh * 128 + colg * 32 + cf * 16 + l15;
                f32x4 av = acc[fr][cf];
#pragma unroll
                for (int i = 0; i < 4; i++) {
                    int r = rb0 + i;
                    if constexpr (FINAL) {
                        if (r < N) Of[(size_t)r * NCOLTOT + colw] = av[i] + bbv[cf];
                    } else {
                        float v = av[i];
                        if constexpr (BIAS) v += bbv[cf];
                        bf16_t hv = (bf16_t)v;
                        if (r < N) Obf[(size_t)r * 256 + colw] = hv;
                        if constexpr (STATS) {
                            float vv = (r < N) ? (float)hv : 0.f;
                            sA[cf] += vv; qA[cf] += vv * vv;
                        }
                    }
                }
            }
        }
        __syncthreads();   // next-A staged & everyone done with buf
        buf ^= 1;
        t = tn;
    }

    if constexpr (STATS) {
#pragma unroll
        for (int cf = 0; cf < 2; cf++) {
            float s = sA[cf], q = qA[cf];
            s += __shfl_xor(s, 16); s += __shfl_xor(s, 32);
            q += __shfl_xor(q, 16); q += __shfl_xor(q, 32);
            if (lane < 16) {
                int colw = colh * 128 + colg * 32 + cf * 16 + l15;
                atomicAdd(&sums[colw], s);
                atomicAdd(&sqs[colw], q);
            }
        }
    }
}

__global__ void finalize_k(const float* __restrict__ sum, const float* __restrict__ sq,
                           const float* __restrict__ g, const float* __restrict__ b,
                           float2* __restrict__ scsh2, float invN) {
    int t = threadIdx.x;
    float mean = sum[t] * invN;
    float var = sq[t] * invN - mean * mean;
    float s = g[t] * rsqrtf(var + 1e-5f);
    scsh2[t] = make_float2(s, b[t] - mean * s);
}

extern "C" void kernel_launch(void* const* d_in, const int* in_sizes, int n_in,
                              void* d_out, int out_size, void* d_ws, size_t ws_size,
                              hipStream_t stream)
{
    const int N = in_sizes[0] / 128;
    const int E = in_sizes[1] / 2;
    const float* x     = (const float*)d_in[0];
    const void*  ei    = d_in[1];
    const float* lin_w = (const float*)d_in[2];
    const float* lin_b = (const float*)d_in[3];
    const float* eps   = (const float*)d_in[4];
    const float* w1    = (const float*)d_in[5];
    const float* g1    = (const float*)d_in[6];
    const float* b1    = (const float*)d_in[7];
    const float* w2    = (const float*)d_in[8];
    const float* g2    = (const float*)d_in[9];
    const float* b2    = (const float*)d_in[10];
    const float* w3    = (const float*)d_in[11];
    const float* b3    = (const float*)d_in[12];
    float* out = (float*)d_out;

    char* ws = (char*)d_ws;
    size_t o = 0;
    auto alloc = [&](size_t bytes) -> char* {
        char* p = ws + o;
        o = (o + bytes + 255) & ~(size_t)255;
        return p;
    };
    bf16_t*   ha    = (bf16_t*)alloc((size_t)N * 256 * 2);  // [x | agg], later t2
    bf16_t*   hb    = (bf16_t*)alloc((size_t)N * 256 * 2);  // t1
    bf16_t*   wcb   = (bf16_t*)alloc((size_t)256 * 256 * 2);
    bf16_t*   w2b   = (bf16_t*)alloc((size_t)256 * 256 * 2);
    bf16_t*   w3b   = (bf16_t*)alloc((size_t)128 * 256 * 2);
    float*    bcomb = (float*)alloc(256 * 4);
    float*    stats = (float*)alloc(4 * 256 * 4);   // sum1, sq1, sum2, sq2
    float2*   scsh1 = (float2*)alloc(256 * 8);
    float2*   scsh2 = (float2*)alloc(256 * 8);
    int*      bcnt  = (int*)alloc(1024 * 4);
    int*      boffs = (int*)alloc(1025 * 4);
    int*      gcur  = (int*)alloc(1024 * 4);
    int*      offs  = (int*)alloc((size_t)(N + 1) * 4);
    unsigned* pairs = (unsigned*)alloc((size_t)E * 4);
    int*      csr   = (int*)alloc((size_t)E * 4);
    int*      flag  = (int*)alloc(4);

    const int NBK = (N + 127) >> 7;

    hipMemsetAsync(bcnt, 0, 1024 * 4, stream);
    hipMemsetAsync(stats, 0, 4 * 256 * 4, stream);
    hipMemsetAsync(flag, 0, 4, stream);

    // conversions / weight prep
    int nx8 = N * 16;
    conv_x_k<<<(nx8 + 255) / 256, 256, 0, stream>>>(x, ha, nx8);
    wcomb_k<<<256, 256, 0, stream>>>(w1, lin_w, lin_b, eps, wcb, bcomb);
    conv_k<<<32, 256, 0, stream>>>(w2, w2b, 8192);
    conv_k<<<16, 256, 0, stream>>>(w3, w3b, 4096);

    // two-level bucket sort of edges -> per-node CSR (all writes coalesced)
    const int nch = (E + CHUNK - 1) / CHUNK;
    detect_k<<<1, 256, 0, stream>>>((const int*)ei, flag);
    bhist_k<<<nch, 256, 0, stream>>>(ei, flag, E, bcnt);
    bscan_k<<<1, 1024, 0, stream>>>(bcnt, boffs, gcur, offs, NBK, N, E);
    binfill_k<<<nch, 256, 0, stream>>>(ei, flag, E, NBK, gcur, pairs);
    bsort2_k<<<NBK, 256, 0, stream>>>(pairs, boffs, offs, csr, N);
    gather_k<<<(N + 3) / 4, 256, 0, stream>>>(ha, offs, csr, N);

    const int nt64 = (N + 63) / 64;
    // t1 = [x|agg] @ Wc^T + bcomb (+ BN1 stats)
    gemm_w<2, false, true, false, true><<<512, 512, 0, stream>>>(
        ha, wcb, nullptr, stats + 0, stats + 256, bcomb, hb, nullptr, N, nt64);
    finalize_k<<<1, 256, 0, stream>>>(stats + 0, stats + 256, g1, b1, scsh1, 1.f / (float)N);
    // t2 = relu(BN1(t1))@w2^T (+ BN2 stats)
    gemm_w<2, true, true, false, false><<<512, 512, 0, stream>>>(
        hb, w2b, scsh1, stats + 512, stats + 768, nullptr, ha, nullptr, N, nt64);
    finalize_k<<<1, 256, 0, stream>>>(stats + 512, stats + 768, g2, b2, scsh2, 1.f / (float)N);
    // out = relu(BN2(t2))@w3^T + b3
    gemm_w<1, true, false, true, true><<<256, 512, 0, stream>>>(
        ha, w3b, scsh2, nullptr, nullptr, b3, nullptr, out, N, nt64);
}

// Round 13
// 296.933 us; speedup vs baseline: 1.2055x; 1.0418x over previous
//
#include <hip/hip_runtime.h>
#include <cstdint>
#include <cstddef>

typedef __bf16 bf16_t;
typedef __bf16 bf16x8 __attribute__((ext_vector_type(8)));
typedef float f32x4 __attribute__((ext_vector_type(4)));

#define GLOBAL_AS __attribute__((address_space(1)))
#define LDS_AS    __attribute__((address_space(3)))

__device__ __forceinline__ void glds16(const void* g, void* l) {
    __builtin_amdgcn_global_load_lds((const GLOBAL_AS void*)g, (LDS_AS void*)l, 16, 0, 0);
}

// ---------------- conversions ----------------
__global__ void conv_k(const float* __restrict__ in, bf16_t* __restrict__ out, int n8) {
    int id = blockIdx.x * 256 + threadIdx.x;
    if (id >= n8) return;
    const float4* p = (const float4*)in;
    float4 a = p[2 * id], b = p[2 * id + 1];
    bf16x8 o;
    o[0] = (bf16_t)a.x; o[1] = (bf16_t)a.y; o[2] = (bf16_t)a.z; o[3] = (bf16_t)a.w;
    o[4] = (bf16_t)b.x; o[5] = (bf16_t)b.y; o[6] = (bf16_t)b.z; o[7] = (bf16_t)b.w;
    *(bf16x8*)(out + (size_t)id * 8) = o;
}

// x fp32 -> cols 0..127 of interleaved ha[N][256]
__global__ void conv_x_k(const float* __restrict__ in, bf16_t* __restrict__ ha, int n8) {
    int id = blockIdx.x * 256 + threadIdx.x;
    if (id >= n8) return;
    const float4* p = (const float4*)in;
    float4 a = p[2 * id], b = p[2 * id + 1];
    bf16x8 o;
    o[0] = (bf16_t)a.x; o[1] = (bf16_t)a.y; o[2] = (bf16_t)a.z; o[3] = (bf16_t)a.w;
    o[4] = (bf16_t)b.x; o[5] = (bf16_t)b.y; o[6] = (bf16_t)b.z; o[7] = (bf16_t)b.w;
    int row = id >> 4, ch = id & 15;
    *(bf16x8*)(ha + (size_t)row * 256 + ch * 8) = o;
}

// ---------------- merged weight: Wc = w1 @ W0, bcomb = w1 @ lin_b ----------------
__global__ void wcomb_k(const float* __restrict__ w1, const float* __restrict__ lin_w,
                        const float* __restrict__ lin_b, const float* __restrict__ eps_p,
                        bf16_t* __restrict__ wc, float* __restrict__ bcomb) {
    __shared__ float red[256];
    int c = blockIdx.x, t = threadIdx.x;
    const float* w1row = w1 + c * 256;
    float onepe = 1.f + *eps_p;
    float v;
    if (t < 128) {
        float acc = 0.f;
        for (int j = 0; j < 256; j++) acc += w1row[j] * lin_w[j * 128 + t];
        v = acc + onepe * (w1row[t] + w1row[t + 128]);
    } else {
        int m = t - 128;
        v = w1row[m] + w1row[t];
    }
    wc[c * 256 + t] = (bf16_t)v;
    red[t] = w1row[t] * lin_b[t];
    __syncthreads();
    for (int off = 128; off > 0; off >>= 1) {
        if (t < off) red[t] += red[t + off];
        __syncthreads();
    }
    if (t == 0) bcomb[c] = red[0];
}

// ---------------- edge-index dtype detection ----------------
__global__ void detect_k(const int* __restrict__ ei, int* __restrict__ flag) {
    int v = ei[2 * threadIdx.x + 1];
    if (v != 0) atomicOr(flag, 1);   // 1 => int32 layout
}

// ---------------- bucket sort of edges (bucket = dst >> 7, 128 nodes/bucket) ----------------
#define CHUNK 8192

__global__ __launch_bounds__(256) void bhist_k(const void* __restrict__ ei, const int* __restrict__ flag,
                                               int E, int* __restrict__ bcnt) {
    __shared__ int cnt[1024];
    int t = threadIdx.x;
    for (int b = t; b < 1024; b += 256) cnt[b] = 0;
    __syncthreads();
    int base = blockIdx.x * CHUNK;
    int i32 = *flag;
#pragma unroll 4
    for (int i = 0; i < CHUNK / 256; i++) {
        int e = base + t + 256 * i;
        if (e < E) {
            int dst = i32 ? ((const int*)ei)[e] : (int)((const long long*)ei)[e];
            atomicAdd(&cnt[dst >> 7], 1);
        }
    }
    __syncthreads();
    for (int b = t; b < 1024; b += 256)
        if (cnt[b]) atomicAdd(&bcnt[b], cnt[b]);
}

__global__ __launch_bounds__(1024) void bscan_k(const int* __restrict__ bcnt, int* __restrict__ boffs,
                                                int* __restrict__ gcur, int* __restrict__ offs,
                                                int NBK, int N, int E) {
    __shared__ int lds[1024];
    int t = threadIdx.x;
    int v = (t < NBK) ? bcnt[t] : 0;
    lds[t] = v;
    __syncthreads();
    for (int off = 1; off < 1024; off <<= 1) {
        int add = (t >= off) ? lds[t - off] : 0;
        __syncthreads();
        lds[t] += add;
        __syncthreads();
    }
    if (t < NBK) {
        int excl = lds[t] - v;
        boffs[t] = excl;
        gcur[t] = excl;
    }
    if (t == 0) { boffs[NBK] = E; offs[N] = E; }
}

// per-block multisplit: LDS hist -> LDS scan -> LDS placement -> coalesced flush
__global__ __launch_bounds__(256) void binfill_k(const void* __restrict__ ei, const int* __restrict__ flag,
                                                 int E, int NBK, int* __restrict__ gcur,
                                                 unsigned* __restrict__ pairs) {
    __shared__ int cnt[1024];
    __shared__ int pref[1024];
    __shared__ int cur[1024];
    __shared__ int gbase[1024];
    __shared__ int red[256];
    __shared__ unsigned slot[CHUNK];
    int t = threadIdx.x;
    int base = blockIdx.x * CHUNK;
    int chunk_n = E - base; if (chunk_n > CHUNK) chunk_n = CHUNK;
    int i32 = *flag;
    for (int b = t; b < 1024; b += 256) cnt[b] = 0;
    __syncthreads();
    // pass 1: hist
#pragma unroll 4
    for (int i = 0; i < CHUNK / 256; i++) {
        int e = base + t + 256 * i;
        if (e < E) {
            int dst = i32 ? ((const int*)ei)[e] : (int)((const long long*)ei)[e];
            atomicAdd(&cnt[dst >> 7], 1);
        }
    }
    __syncthreads();
    // scan cnt[1024] with 256 threads (4 per thread)
    int t4 = t * 4;
    int c0 = cnt[t4], c1 = cnt[t4 + 1], c2 = cnt[t4 + 2], c3 = cnt[t4 + 3];
    int s = c0 + c1 + c2 + c3;
    red[t] = s;
    __syncthreads();
    for (int off = 1; off < 256; off <<= 1) {
        int add = (t >= off) ? red[t - off] : 0;
        __syncthreads();
        red[t] += add;
        __syncthreads();
    }
    int run = red[t] - s;
    pref[t4] = run; cur[t4] = run; run += c0;
    pref[t4 + 1] = run; cur[t4 + 1] = run; run += c1;
    pref[t4 + 2] = run; cur[t4 + 2] = run; run += c2;
    pref[t4 + 3] = run; cur[t4 + 3] = run;
    __syncthreads();
    // pass 2: place into LDS slots
#pragma unroll 4
    for (int i = 0; i < CHUNK / 256; i++) {
        int e = base + t + 256 * i;
        if (e < E) {
            int dst, src;
            if (i32) { dst = ((const int*)ei)[e]; src = ((const int*)ei)[E + e]; }
            else     { dst = (int)((const long long*)ei)[e]; src = (int)((const long long*)ei)[E + e]; }
            int b = dst >> 7;
            int p = atomicAdd(&cur[b], 1);
            slot[p] = ((unsigned)(dst & 127) << 20) | (unsigned)src;
        }
    }
    __syncthreads();
    // per-bucket global base
    for (int b = t; b < 1024; b += 256) {
        int c = (b + 1 < 1024) ? (pref[b + 1] - pref[b]) : (chunk_n - pref[b]);
        if (b < NBK && c > 0) gbase[b] = atomicAdd(&gcur[b], c);
    }
    __syncthreads();
    // coalesced flush: consecutive lanes -> consecutive slots
    for (int i = t; i < chunk_n; i += 256) {
        int lo = 0, hi = NBK - 1;
        while (lo < hi) {
            int mid = (lo + hi + 1) >> 1;
            if (pref[mid] <= i) lo = mid; else hi = mid - 1;
        }
        pairs[gbase[lo] + (i - pref[lo])] = slot[i];
    }
}

// level-2 counting sort: one block per bucket -> per-node CSR + offs
__global__ __launch_bounds__(256) void bsort2_k(const unsigned* __restrict__ pairs,
                                                const int* __restrict__ boffs,
                                                int* __restrict__ offs,
                                                int* __restrict__ csr, int N) {
    __shared__ int cnt[128], pref[128], cur[128];
    int t = threadIdx.x;
    int b = blockIdx.x;
    int s = boffs[b], e = boffs[b + 1];
    if (t < 128) cnt[t] = 0;
    __syncthreads();
    for (int i = s + t; i < e; i += 256)
        atomicAdd(&cnt[pairs[i] >> 20], 1);
    __syncthreads();
    if (t < 128) pref[t] = cnt[t];
    __syncthreads();
    for (int off = 1; off < 128; off <<= 1) {
        int v = 0;
        if (t < 128 && t >= off) v = pref[t - off];
        __syncthreads();
        if (t < 128) pref[t] += v;
        __syncthreads();
    }
    if (t < 128) {
        int ex = pref[t] - cnt[t];      // exclusive prefix
        cur[t] = ex;
        int node = b * 128 + t;
        if (node < N) offs[node] = s + ex;
    }
    __syncthreads();
    for (int i = s + t; i < e; i += 256) {
        unsigned u = pairs[i];
        int dl = (int)(u >> 20);
        int p = atomicAdd(&cur[dl], 1);
        csr[s + p] = (int)(u & 0xFFFFFu);
    }
}

// one wave per node; 8 neighbor rows in flight (2x unrolled), 16 lanes x 16B per row
__global__ __launch_bounds__(256) void gather_k(bf16_t* __restrict__ ha, const int* __restrict__ offs,
                                                const int* __restrict__ csr, int N) {
    int w = (blockIdx.x * 256 + threadIdx.x) >> 6;
    if (w >= N) return;
    int lane = threadIdx.x & 63;
    int g = lane >> 4, l15 = lane & 15;
    int s = offs[w], e = offs[w + 1];
    float acc[8] = {0.f, 0.f, 0.f, 0.f, 0.f, 0.f, 0.f, 0.f};
    float acc2[8] = {0.f, 0.f, 0.f, 0.f, 0.f, 0.f, 0.f, 0.f};
    int i = s + g;
    for (; i + 4 < e; i += 8) {
        int s0 = csr[i];
        int s1 = csr[i + 4];
        bf16x8 v0 = *(const bf16x8*)(ha + (size_t)s0 * 256 + l15 * 8);
        bf16x8 v1 = *(const bf16x8*)(ha + (size_t)s1 * 256 + l15 * 8);
#pragma unroll
        for (int j = 0; j < 8; j++) { acc[j] += (float)v0[j]; acc2[j] += (float)v1[j]; }
    }
    if (i < e) {
        int s0 = csr[i];
        bf16x8 v0 = *(const bf16x8*)(ha + (size_t)s0 * 256 + l15 * 8);
#pragma unroll
        for (int j = 0; j < 8; j++) acc[j] += (float)v0[j];
    }
#pragma unroll
    for (int j = 0; j < 8; j++) {
        acc[j] += acc2[j];
        acc[j] += __shfl_xor(acc[j], 16);
        acc[j] += __shfl_xor(acc[j], 32);
    }
    if (g == 0) {
        bf16x8 o;
#pragma unroll
        for (int j = 0; j < 8; j++) o[j] = (bf16_t)acc[j];
        *(bf16x8*)(ha + (size_t)w * 256 + 128 + l15 * 8) = o;
    }
}

// ---------------- W-resident + A-LDS-tiled K=256 MFMA GEMM ----------------
// Same structure as R12 (76us, no spills) with the W bank-conflict FIXED:
// cols are 512B apart in LDS (all start at bank 0), so the fragment-read XOR
// must spread the 16 consecutive l15-cols over all 8 16B slots. R12 used
// ((col>>1)&3)<<4 -> only 4 slots -> 4-way conflict on every W ds_read_b128
// (the measured 6.4M conflicts). Now: (col&7)<<4 -> 8 slots x 2 lanes = 2-way
// = free (m136). A-side (row&7)<<4 already 2-way. Swizzle applied identically
// on the glds global-source (stage) and the ds_read address (m173 pattern).
// mfma_f32_16x16x32_bf16 (m89): A lane A[l&15][(l>>4)*8+i]; B lane B[k][l&15];
// D reg i <-> out[row=(l>>4)*4+i][col=l&15].
template<int NHALF, bool BNIN, bool STATS, bool FINAL, bool BIAS>
__global__ __launch_bounds__(512, 1) void gemm_w(
    const bf16_t* __restrict__ A, const bf16_t* __restrict__ W,
    const float2* __restrict__ scsh2,
    float* __restrict__ sums, float* __restrict__ sqs,
    const float* __restrict__ bias,
    bf16_t* __restrict__ Obf, float* __restrict__ Of, int N, int ntiles)
{
    constexpr int NCOLTOT = NHALF * 128;
    __shared__ __align__(16) char smemW[65536];      // 128 cols x 512B
    __shared__ __align__(16) char smemA[2][32768];   // 2 x (64 rows x 512B)
    __shared__ float2 ssl[BNIN ? 256 : 1];

    const int tid = threadIdx.x;
    const int lane = tid & 63, wid = tid >> 6;
    const int l15 = lane & 15, l4 = lane >> 4;
    const int rowg = wid & 1, colg = wid >> 1;       // 2 rowg x 4 colg
    const int colh = blockIdx.x % NHALF;
    const int rb = blockIdx.x / NHALF;               // row-stride id in [0,256)

    if constexpr (BNIN) { if (tid < 256) ssl[tid] = scsh2[tid]; }

    // stage the W column-half (64KB) once: swizzled global source, linear LDS
#pragma unroll
    for (int it = 0; it < 8; it++) {
        int d = (it * 512 + tid) * 16;
        int col = d >> 9, koff = d & 511;
        int ksw = koff ^ ((col & 7) << 4);
        glds16((const char*)W + (size_t)(colh * 128 + col) * 512 + ksw, smemW + d);
    }

    auto stageA = [&](int buf, int t) {
        size_t rowbase = (size_t)t * 64;
#pragma unroll
        for (int it = 0; it < 4; it++) {
            int d = (it * 512 + tid) * 16;
            int row = d >> 9, koff = d & 511;
            int ksw = koff ^ ((row & 7) << 4);
            glds16((const char*)A + (rowbase + row) * 512 + ksw, smemA[buf] + d);
        }
    };

    float bbv[2];
    if constexpr (BIAS || FINAL) {
#pragma unroll
        for (int cf = 0; cf < 2; cf++)
            bbv[cf] = bias[colh * 128 + colg * 32 + cf * 16 + l15];
    }
    float sA[2], qA[2];
    if constexpr (STATS) { sA[0] = sA[1] = qA[0] = qA[1] = 0.f; }

    int t = rb;
    if (t < ntiles) stageA(0, t);
    __syncthreads();

    int buf = 0;
    while (t < ntiles) {
        int tn = t + 256;
        if (tn < ntiles) stageA(buf ^ 1, tn);

        // compute 64x128 tile: wave = 32 rows (rowg) x 32 cols (colg)
        f32x4 acc[2][2];
#pragma unroll
        for (int i = 0; i < 2; i++) { acc[i][0] = f32x4{0.f,0.f,0.f,0.f}; acc[i][1] = f32x4{0.f,0.f,0.f,0.f}; }
#pragma unroll
        for (int c = 0; c < 8; c++) {
            const int koff = c * 64 + l4 * 16;
            bf16x8 a[2];
#pragma unroll
            for (int fr = 0; fr < 2; fr++) {
                int row = rowg * 32 + fr * 16 + l15;
                a[fr] = *(const bf16x8*)(smemA[buf] + row * 512 + (koff ^ ((row & 7) << 4)));
            }
            if constexpr (BNIN) {
                const int k0 = c * 32 + l4 * 8;
#pragma unroll
                for (int fr = 0; fr < 2; fr++) {
                    bf16x8 tt;
#pragma unroll
                    for (int i = 0; i < 8; i++) {
                        float2 ss = ssl[k0 + i];
                        float f = (float)a[fr][i] * ss.x + ss.y;
                        tt[i] = (bf16_t)fmaxf(f, 0.f);
                    }
                    a[fr] = tt;
                }
            }
#pragma unroll
            for (int cf = 0; cf < 2; cf++) {
                int col = colg * 32 + cf * 16 + l15;
                const bf16x8 b = *(const bf16x8*)(smemW + col * 512 + (koff ^ ((col & 7) << 4)));
                acc[0][cf] = __builtin_amdgcn_mfma_f32_16x16x32_bf16(a[0], b, acc[0][cf], 0, 0, 0);
                acc[1][cf] = __builtin_amdgcn_mfma_f32_16x16x32_bf16(a[1], b, acc[1][cf], 0, 0, 0);
            }
        }

        // epilogue: direct scatter stores (clean per R3/R10) + register stats
        const int rows0 = t * 64 + rowg * 32;
#pragma unroll
        for (int fr = 0; fr < 2; fr++) {
            int rb0 = rows0 + fr * 16 + l4 * 4;
#pragma unroll
            for (int cf = 0; cf < 2; cf++) {
                int colw = colh * 128 + colg * 32 + cf * 16 + l15;
                f32x4 av = acc[fr][cf];
#pragma unroll
                for (int i = 0; i < 4; i++) {
                    int r = rb0 + i;
                    if constexpr (FINAL) {
                        if (r < N) Of[(size_t)r * NCOLTOT + colw] = av[i] + bbv[cf];
                    } else {
                        float v = av[i];
                        if constexpr (BIAS) v += bbv[cf];
                        bf16_t hv = (bf16_t)v;
                        if (r < N) Obf[(size_t)r * 256 + colw] = hv;
                        if constexpr (STATS) {
                            float vv = (r < N) ? (float)hv : 0.f;
                            sA[cf] += vv; qA[cf] += vv * vv;
                        }
                    }
                }
            }
        }
        __syncthreads();   // next-A staged & everyone done with buf
        buf ^= 1;
        t = tn;
    }

    if constexpr (STATS) {
#pragma unroll
        for (int cf = 0; cf < 2; cf++) {
            float s = sA[cf], q = qA[cf];
            s += __shfl_xor(s, 16); s += __shfl_xor(s, 32);
            q += __shfl_xor(q, 16); q += __shfl_xor(q, 32);
            if (lane < 16) {
                int colw = colh * 128 + colg * 32 + cf * 16 + l15;
                atomicAdd(&sums[colw], s);
                atomicAdd(&sqs[colw], q);
            }
        }
    }
}

__global__ void finalize_k(const float* __restrict__ sum, const float* __restrict__ sq,
                           const float* __restrict__ g, const float* __restrict__ b,
                           float2* __restrict__ scsh2, float invN) {
    int t = threadIdx.x;
    float mean = sum[t] * invN;
    float var = sq[t] * invN - mean * mean;
    float s = g[t] * rsqrtf(var + 1e-5f);
    scsh2[t] = make_float2(s, b[t] - mean * s);
}

extern "C" void kernel_launch(void* const* d_in, const int* in_sizes, int n_in,
                              void* d_out, int out_size, void* d_ws, size_t ws_size,
                              hipStream_t stream)
{
    const int N = in_sizes[0] / 128;
    const int E = in_sizes[1] / 2;
    const float* x     = (const float*)d_in[0];
    const void*  ei    = d_in[1];
    const float* lin_w = (const float*)d_in[2];
    const float* lin_b = (const float*)d_in[3];
    const float* eps   = (const float*)d_in[4];
    const float* w1    = (const float*)d_in[5];
    const float* g1    = (const float*)d_in[6];
    const float* b1    = (const float*)d_in[7];
    const float* w2    = (const float*)d_in[8];
    const float* g2    = (const float*)d_in[9];
    const float* b2    = (const float*)d_in[10];
    const float* w3    = (const float*)d_in[11];
    const float* b3    = (const float*)d_in[12];
    float* out = (float*)d_out;

    char* ws = (char*)d_ws;
    size_t o = 0;
    auto alloc = [&](size_t bytes) -> char* {
        char* p = ws + o;
        o = (o + bytes + 255) & ~(size_t)255;
        return p;
    };
    bf16_t*   ha    = (bf16_t*)alloc((size_t)N * 256 * 2);  // [x | agg], later t2
    bf16_t*   hb    = (bf16_t*)alloc((size_t)N * 256 * 2);  // t1
    bf16_t*   wcb   = (bf16_t*)alloc((size_t)256 * 256 * 2);
    bf16_t*   w2b   = (bf16_t*)alloc((size_t)256 * 256 * 2);
    bf16_t*   w3b   = (bf16_t*)alloc((size_t)128 * 256 * 2);
    float*    bcomb = (float*)alloc(256 * 4);
    float*    stats = (float*)alloc(4 * 256 * 4);   // sum1, sq1, sum2, sq2
    float2*   scsh1 = (float2*)alloc(256 * 8);
    float2*   scsh2 = (float2*)alloc(256 * 8);
    int*      bcnt  = (int*)alloc(1024 * 4);
    int*      boffs = (int*)alloc(1025 * 4);
    int*      gcur  = (int*)alloc(1024 * 4);
    int*      offs  = (int*)alloc((size_t)(N + 1) * 4);
    unsigned* pairs = (unsigned*)alloc((size_t)E * 4);
    int*      csr   = (int*)alloc((size_t)E * 4);
    int*      flag  = (int*)alloc(4);

    const int NBK = (N + 127) >> 7;

    hipMemsetAsync(bcnt, 0, 1024 * 4, stream);
    hipMemsetAsync(stats, 0, 4 * 256 * 4, stream);
    hipMemsetAsync(flag, 0, 4, stream);

    // conversions / weight prep
    int nx8 = N * 16;
    conv_x_k<<<(nx8 + 255) / 256, 256, 0, stream>>>(x, ha, nx8);
    wcomb_k<<<256, 256, 0, stream>>>(w1, lin_w, lin_b, eps, wcb, bcomb);
    conv_k<<<32, 256, 0, stream>>>(w2, w2b, 8192);
    conv_k<<<16, 256, 0, stream>>>(w3, w3b, 4096);

    // two-level bucket sort of edges -> per-node CSR (all writes coalesced)
    const int nch = (E + CHUNK - 1) / CHUNK;
    detect_k<<<1, 256, 0, stream>>>((const int*)ei, flag);
    bhist_k<<<nch, 256, 0, stream>>>(ei, flag, E, bcnt);
    bscan_k<<<1, 1024, 0, stream>>>(bcnt, boffs, gcur, offs, NBK, N, E);
    binfill_k<<<nch, 256, 0, stream>>>(ei, flag, E, NBK, gcur, pairs);
    bsort2_k<<<NBK, 256, 0, stream>>>(pairs, boffs, offs, csr, N);
    gather_k<<<(N + 3) / 4, 256, 0, stream>>>(ha, offs, csr, N);

    const int nt64 = (N + 63) / 64;
    // t1 = [x|agg] @ Wc^T + bcomb (+ BN1 stats)
    gemm_w<2, false, true, false, true><<<512, 512, 0, stream>>>(
        ha, wcb, nullptr, stats + 0, stats + 256, bcomb, hb, nullptr, N, nt64);
    finalize_k<<<1, 256, 0, stream>>>(stats + 0, stats + 256, g1, b1, scsh1, 1.f / (float)N);
    // t2 = relu(BN1(t1))@w2^T (+ BN2 stats)
    gemm_w<2, true, true, false, false><<<512, 512, 0, stream>>>(
        hb, w2b, scsh1, stats + 512, stats + 768, nullptr, ha, nullptr, N, nt64);
    finalize_k<<<1, 256, 0, stream>>>(stats + 512, stats + 768, g2, b2, scsh2, 1.f / (float)N);
    // out = relu(BN2(t2))@w3^T + b3
    gemm_w<1, true, false, true, true><<<256, 512, 0, stream>>>(
        ha, w3b, scsh2, nullptr, nullptr, b3, nullptr, out, N, nt64);
}

// Round 14
// 267.483 us; speedup vs baseline: 1.3383x; 1.1101x over previous
//
#include <hip/hip_runtime.h>
#include <cstdint>
#include <cstddef>

typedef __bf16 bf16_t;
typedef __bf16 bf16x8 __attribute__((ext_vector_type(8)));
typedef float f32x4 __attribute__((ext_vector_type(4)));

#define GLOBAL_AS __attribute__((address_space(1)))
#define LDS_AS    __attribute__((address_space(3)))

__device__ __forceinline__ void glds16(const void* g, void* l) {
    __builtin_amdgcn_global_load_lds((const GLOBAL_AS void*)g, (LDS_AS void*)l, 16, 0, 0);
}

// ---------------- conversions ----------------
__global__ void conv_k(const float* __restrict__ in, bf16_t* __restrict__ out, int n8) {
    int id = blockIdx.x * 256 + threadIdx.x;
    if (id >= n8) return;
    const float4* p = (const float4*)in;
    float4 a = p[2 * id], b = p[2 * id + 1];
    bf16x8 o;
    o[0] = (bf16_t)a.x; o[1] = (bf16_t)a.y; o[2] = (bf16_t)a.z; o[3] = (bf16_t)a.w;
    o[4] = (bf16_t)b.x; o[5] = (bf16_t)b.y; o[6] = (bf16_t)b.z; o[7] = (bf16_t)b.w;
    *(bf16x8*)(out + (size_t)id * 8) = o;
}

// x fp32 -> cols 0..127 of interleaved ha[N][256]
__global__ void conv_x_k(const float* __restrict__ in, bf16_t* __restrict__ ha, int n8) {
    int id = blockIdx.x * 256 + threadIdx.x;
    if (id >= n8) return;
    const float4* p = (const float4*)in;
    float4 a = p[2 * id], b = p[2 * id + 1];
    bf16x8 o;
    o[0] = (bf16_t)a.x; o[1] = (bf16_t)a.y; o[2] = (bf16_t)a.z; o[3] = (bf16_t)a.w;
    o[4] = (bf16_t)b.x; o[5] = (bf16_t)b.y; o[6] = (bf16_t)b.z; o[7] = (bf16_t)b.w;
    int row = id >> 4, ch = id & 15;
    *(bf16x8*)(ha + (size_t)row * 256 + ch * 8) = o;
}

// ---------------- merged weight: Wc = w1 @ W0, bcomb = w1 @ lin_b ----------------
__global__ void wcomb_k(const float* __restrict__ w1, const float* __restrict__ lin_w,
                        const float* __restrict__ lin_b, const float* __restrict__ eps_p,
                        bf16_t* __restrict__ wc, float* __restrict__ bcomb) {
    __shared__ float red[256];
    int c = blockIdx.x, t = threadIdx.x;
    const float* w1row = w1 + c * 256;
    float onepe = 1.f + *eps_p;
    float v;
    if (t < 128) {
        float acc = 0.f;
        for (int j = 0; j < 256; j++) acc += w1row[j] * lin_w[j * 128 + t];
        v = acc + onepe * (w1row[t] + w1row[t + 128]);
    } else {
        int m = t - 128;
        v = w1row[m] + w1row[t];
    }
    wc[c * 256 + t] = (bf16_t)v;
    red[t] = w1row[t] * lin_b[t];
    __syncthreads();
    for (int off = 128; off > 0; off >>= 1) {
        if (t < off) red[t] += red[t + off];
        __syncthreads();
    }
    if (t == 0) bcomb[c] = red[0];
}

// ---------------- edge-index dtype detection ----------------
__global__ void detect_k(const int* __restrict__ ei, int* __restrict__ flag) {
    int v = ei[2 * threadIdx.x + 1];
    if (v != 0) atomicOr(flag, 1);   // 1 => int32 layout
}

// ---------------- bucket sort of edges (bucket = dst >> 7, 128 nodes/bucket) ----------------
#define CHUNK 8192

__global__ __launch_bounds__(256) void bhist_k(const void* __restrict__ ei, const int* __restrict__ flag,
                                               int E, int* __restrict__ bcnt) {
    __shared__ int cnt[1024];
    int t = threadIdx.x;
    for (int b = t; b < 1024; b += 256) cnt[b] = 0;
    __syncthreads();
    int base = blockIdx.x * CHUNK;
    int i32 = *flag;
#pragma unroll 4
    for (int i = 0; i < CHUNK / 256; i++) {
        int e = base + t + 256 * i;
        if (e < E) {
            int dst = i32 ? ((const int*)ei)[e] : (int)((const long long*)ei)[e];
            atomicAdd(&cnt[dst >> 7], 1);
        }
    }
    __syncthreads();
    for (int b = t; b < 1024; b += 256)
        if (cnt[b]) atomicAdd(&bcnt[b], cnt[b]);
}

__global__ __launch_bounds__(1024) void bscan_k(const int* __restrict__ bcnt, int* __restrict__ boffs,
                                                int* __restrict__ gcur, int* __restrict__ offs,
                                                int NBK, int N, int E) {
    __shared__ int lds[1024];
    int t = threadIdx.x;
    int v = (t < NBK) ? bcnt[t] : 0;
    lds[t] = v;
    __syncthreads();
    for (int off = 1; off < 1024; off <<= 1) {
        int add = (t >= off) ? lds[t - off] : 0;
        __syncthreads();
        lds[t] += add;
        __syncthreads();
    }
    if (t < NBK) {
        int excl = lds[t] - v;
        boffs[t] = excl;
        gcur[t] = excl;
    }
    if (t == 0) { boffs[NBK] = E; offs[N] = E; }
}

// per-block multisplit: LDS hist -> LDS scan -> LDS placement -> coalesced flush
__global__ __launch_bounds__(256) void binfill_k(const void* __restrict__ ei, const int* __restrict__ flag,
                                                 int E, int NBK, int* __restrict__ gcur,
                                                 unsigned* __restrict__ pairs) {
    __shared__ int cnt[1024];
    __shared__ int pref[1024];
    __shared__ int cur[1024];
    __shared__ int gbase[1024];
    __shared__ int red[256];
    __shared__ unsigned slot[CHUNK];
    int t = threadIdx.x;
    int base = blockIdx.x * CHUNK;
    int chunk_n = E - base; if (chunk_n > CHUNK) chunk_n = CHUNK;
    int i32 = *flag;
    for (int b = t; b < 1024; b += 256) cnt[b] = 0;
    __syncthreads();
    // pass 1: hist
#pragma unroll 4
    for (int i = 0; i < CHUNK / 256; i++) {
        int e = base + t + 256 * i;
        if (e < E) {
            int dst = i32 ? ((const int*)ei)[e] : (int)((const long long*)ei)[e];
            atomicAdd(&cnt[dst >> 7], 1);
        }
    }
    __syncthreads();
    // scan cnt[1024] with 256 threads (4 per thread)
    int t4 = t * 4;
    int c0 = cnt[t4], c1 = cnt[t4 + 1], c2 = cnt[t4 + 2], c3 = cnt[t4 + 3];
    int s = c0 + c1 + c2 + c3;
    red[t] = s;
    __syncthreads();
    for (int off = 1; off < 256; off <<= 1) {
        int add = (t >= off) ? red[t - off] : 0;
        __syncthreads();
        red[t] += add;
        __syncthreads();
    }
    int run = red[t] - s;
    pref[t4] = run; cur[t4] = run; run += c0;
    pref[t4 + 1] = run; cur[t4 + 1] = run; run += c1;
    pref[t4 + 2] = run; cur[t4 + 2] = run; run += c2;
    pref[t4 + 3] = run; cur[t4 + 3] = run;
    __syncthreads();
    // pass 2: place into LDS slots
#pragma unroll 4
    for (int i = 0; i < CHUNK / 256; i++) {
        int e = base + t + 256 * i;
        if (e < E) {
            int dst, src;
            if (i32) { dst = ((const int*)ei)[e]; src = ((const int*)ei)[E + e]; }
            else     { dst = (int)((const long long*)ei)[e]; src = (int)((const long long*)ei)[E + e]; }
            int b = dst >> 7;
            int p = atomicAdd(&cur[b], 1);
            slot[p] = ((unsigned)(dst & 127) << 20) | (unsigned)src;
        }
    }
    __syncthreads();
    // per-bucket global base
    for (int b = t; b < 1024; b += 256) {
        int c = (b + 1 < 1024) ? (pref[b + 1] - pref[b]) : (chunk_n - pref[b]);
        if (b < NBK && c > 0) gbase[b] = atomicAdd(&gcur[b], c);
    }
    __syncthreads();
    // coalesced flush: consecutive lanes -> consecutive slots
    for (int i = t; i < chunk_n; i += 256) {
        int lo = 0, hi = NBK - 1;
        while (lo < hi) {
            int mid = (lo + hi + 1) >> 1;
            if (pref[mid] <= i) lo = mid; else hi = mid - 1;
        }
        pairs[gbase[lo] + (i - pref[lo])] = slot[i];
    }
}

// level-2 counting sort: one block per bucket -> per-node CSR + offs
__global__ __launch_bounds__(256) void bsort2_k(const unsigned* __restrict__ pairs,
                                                const int* __restrict__ boffs,
                                                int* __restrict__ offs,
                                                int* __restrict__ csr, int N) {
    __shared__ int cnt[128], pref[128], cur[128];
    int t = threadIdx.x;
    int b = blockIdx.x;
    int s = boffs[b], e = boffs[b + 1];
    if (t < 128) cnt[t] = 0;
    __syncthreads();
    for (int i = s + t; i < e; i += 256)
        atomicAdd(&cnt[pairs[i] >> 20], 1);
    __syncthreads();
    if (t < 128) pref[t] = cnt[t];
    __syncthreads();
    for (int off = 1; off < 128; off <<= 1) {
        int v = 0;
        if (t < 128 && t >= off) v = pref[t - off];
        __syncthreads();
        if (t < 128) pref[t] += v;
        __syncthreads();
    }
    if (t < 128) {
        int ex = pref[t] - cnt[t];      // exclusive prefix
        cur[t] = ex;
        int node = b * 128 + t;
        if (node < N) offs[node] = s + ex;
    }
    __syncthreads();
    for (int i = s + t; i < e; i += 256) {
        unsigned u = pairs[i];
        int dl = (int)(u >> 20);
        int p = atomicAdd(&cur[dl], 1);
        csr[s + p] = (int)(u & 0xFFFFFu);
    }
}

// one wave per node; 8 neighbor rows in flight (2x unrolled), 16 lanes x 16B per row
__global__ __launch_bounds__(256) void gather_k(bf16_t* __restrict__ ha, const int* __restrict__ offs,
                                                const int* __restrict__ csr, int N) {
    int w = (blockIdx.x * 256 + threadIdx.x) >> 6;
    if (w >= N) return;
    int lane = threadIdx.x & 63;
    int g = lane >> 4, l15 = lane & 15;
    int s = offs[w], e = offs[w + 1];
    float acc[8] = {0.f, 0.f, 0.f, 0.f, 0.f, 0.f, 0.f, 0.f};
    float acc2[8] = {0.f, 0.f, 0.f, 0.f, 0.f, 0.f, 0.f, 0.f};
    int i = s + g;
    for (; i + 4 < e; i += 8) {
        int s0 = csr[i];
        int s1 = csr[i + 4];
        bf16x8 v0 = *(const bf16x8*)(ha + (size_t)s0 * 256 + l15 * 8);
        bf16x8 v1 = *(const bf16x8*)(ha + (size_t)s1 * 256 + l15 * 8);
#pragma unroll
        for (int j = 0; j < 8; j++) { acc[j] += (float)v0[j]; acc2[j] += (float)v1[j]; }
    }
    if (i < e) {
        int s0 = csr[i];
        bf16x8 v0 = *(const bf16x8*)(ha + (size_t)s0 * 256 + l15 * 8);
#pragma unroll
        for (int j = 0; j < 8; j++) acc[j] += (float)v0[j];
    }
#pragma unroll
    for (int j = 0; j < 8; j++) {
        acc[j] += acc2[j];
        acc[j] += __shfl_xor(acc[j], 16);
        acc[j] += __shfl_xor(acc[j], 32);
    }
    if (g == 0) {
        bf16x8 o;
#pragma unroll
        for (int j = 0; j < 8; j++) o[j] = (bf16_t)acc[j];
        *(bf16x8*)(ha + (size_t)w * 256 + 128 + l15 * 8) = o;
    }
}

// ---------------- W-resident + A-LDS-tiled K=256 MFMA GEMM (v3) ----------------
// R13 structure with three changes:
// (1) BNIN applied ONCE per staged A-tile, in-place in LDS, by all 512 threads
//     (was recomputed 8x: per colg-wave x colh-block). Per-thread scale/shift
//     pairs for its fixed LDS span are hoisted into 32 registers (loaded once) —
//     zero ssl reads in the main loop; compute() is pure ds_read+MFMA.
// (2) Epilogue stores issue AFTER the tile barrier (registers only) — the
//     barrier no longer drains fresh HBM stores; stores age a full tile.
// (3) Grid 512->256 (one persistent round, ~12 tiles/block): one W prologue.
// Swizzles (both-sides m173): A koff^=(row&7)<<4, W koff^=(col&7)<<4 (2-way=free).
// mfma_f32_16x16x32_bf16 (m89): A lane A[l&15][(l>>4)*8+i]; B lane B[k][l&15];
// D reg i <-> out[row=(l>>4)*4+i][col=l&15].
template<int NHALF, bool BNIN, bool STATS, bool FINAL, bool BIAS>
__global__ __launch_bounds__(512, 1) void gemm_w(
    const bf16_t* __restrict__ A, const bf16_t* __restrict__ W,
    const float2* __restrict__ scsh2,
    float* __restrict__ sums, float* __restrict__ sqs,
    const float* __restrict__ bias,
    bf16_t* __restrict__ Obf, float* __restrict__ Of, int N, int ntiles, int tstride)
{
    constexpr int NCOLTOT = NHALF * 128;
    __shared__ __align__(16) char smemW[65536];      // 128 cols x 512B
    __shared__ __align__(16) char smemA[2][32768];   // 2 x (64 rows x 512B)

    const int tid = threadIdx.x;
    const int lane = tid & 63, wid = tid >> 6;
    const int l15 = lane & 15, l4 = lane >> 4;
    const int rowg = wid & 1, colg = wid >> 1;       // 2 rowg x 4 colg
    const int colh = blockIdx.x % NHALF;
    const int rb = blockIdx.x / NHALF;

    // stage the W column-half (64KB) once: swizzled global source, linear LDS
#pragma unroll
    for (int it = 0; it < 8; it++) {
        int d = (it * 512 + tid) * 16;
        int col = d >> 9, koff = d & 511;
        int ksw = koff ^ ((col & 7) << 4);
        glds16((const char*)W + (size_t)(colh * 128 + col) * 512 + ksw, smemW + d);
    }

    auto stageA = [&](int buf, int t) {
        size_t rowbase = (size_t)t * 64;
#pragma unroll
        for (int it = 0; it < 4; it++) {
            int d = (it * 512 + tid) * 16;
            int row = d >> 9, koff = d & 511;
            int ksw = koff ^ ((row & 7) << 4);
            glds16((const char*)A + (rowbase + row) * 512 + ksw, smemA[buf] + d);
        }
    };

    // hoisted per-thread BN scale/shift for this thread's fixed 4x b128 LDS span
    float2 sslr[32];
    if constexpr (BNIN) {
#pragma unroll
        for (int it = 0; it < 4; it++) {
            int d = (it * 512 + tid) * 16;
            int row = d >> 9;
            int k0 = ((d & 511) ^ ((row & 7) << 4)) >> 1;
#pragma unroll
            for (int i = 0; i < 8; i++) sslr[it * 8 + i] = scsh2[k0 + i];
        }
    }

    auto transformA = [&](int buf) {
#pragma unroll
        for (int it = 0; it < 4; it++) {
            int d = (it * 512 + tid) * 16;
            bf16x8 v = *(const bf16x8*)(smemA[buf] + d);
            bf16x8 o;
#pragma unroll
            for (int i = 0; i < 8; i++) {
                float2 ss = sslr[it * 8 + i];
                o[i] = (bf16_t)fmaxf((float)v[i] * ss.x + ss.y, 0.f);
            }
            *(bf16x8*)(smemA[buf] + d) = o;
        }
    };

    float bbv[2];
    if constexpr (BIAS || FINAL) {
#pragma unroll
        for (int cf = 0; cf < 2; cf++)
            bbv[cf] = bias[colh * 128 + colg * 32 + cf * 16 + l15];
    }
    float sA[2], qA[2];
    if constexpr (STATS) { sA[0] = sA[1] = qA[0] = qA[1] = 0.f; }

    f32x4 acc[2][2];

    auto compute = [&](int buf) {
#pragma unroll
        for (int i = 0; i < 2; i++) { acc[i][0] = f32x4{0.f,0.f,0.f,0.f}; acc[i][1] = f32x4{0.f,0.f,0.f,0.f}; }
#pragma unroll
        for (int c = 0; c < 8; c++) {
            const int koff = c * 64 + l4 * 16;
            bf16x8 a[2];
#pragma unroll
            for (int fr = 0; fr < 2; fr++) {
                int row = rowg * 32 + fr * 16 + l15;
                a[fr] = *(const bf16x8*)(smemA[buf] + row * 512 + (koff ^ ((row & 7) << 4)));
            }
#pragma unroll
            for (int cf = 0; cf < 2; cf++) {
                int col = colg * 32 + cf * 16 + l15;
                const bf16x8 b = *(const bf16x8*)(smemW + col * 512 + (koff ^ ((col & 7) << 4)));
                acc[0][cf] = __builtin_amdgcn_mfma_f32_16x16x32_bf16(a[0], b, acc[0][cf], 0, 0, 0);
                acc[1][cf] = __builtin_amdgcn_mfma_f32_16x16x32_bf16(a[1], b, acc[1][cf], 0, 0, 0);
            }
        }
    };

    auto epilogue = [&](int t) {
        const int rows0 = t * 64 + rowg * 32;
#pragma unroll
        for (int fr = 0; fr < 2; fr++) {
            int rb0 = rows0 + fr * 16 + l4 * 4;
#pragma unroll
            for (int cf = 0; cf < 2; cf++) {
                int colw = colh * 128 + colg * 32 + cf * 16 + l15;
                f32x4 av = acc[fr][cf];
#pragma unroll
                for (int i = 0; i < 4; i++) {
                    int r = rb0 + i;
                    if constexpr (FINAL) {
                        if (r < N) Of[(size_t)r * NCOLTOT + colw] = av[i] + bbv[cf];
                    } else {
                        float v = av[i];
                        if constexpr (BIAS) v += bbv[cf];
                        bf16_t hv = (bf16_t)v;
                        if (r < N) Obf[(size_t)r * 256 + colw] = hv;
                        if constexpr (STATS) {
                            float vv = (r < N) ? (float)hv : 0.f;
                            sA[cf] += vv; qA[cf] += vv * vv;
                        }
                    }
                }
            }
        }
    };

    int t = rb;
    int buf = 0;
    if (t < ntiles) stageA(0, t);
    __syncthreads();                  // W + first A staged
    if constexpr (BNIN) {
        if (t < ntiles) transformA(0);
        __syncthreads();
    }

    while (t < ntiles) {
        int tn = t + tstride;
        if (tn < ntiles) stageA(buf ^ 1, tn);
        compute(buf);
        __syncthreads();              // stage(buf^1) aged by compute; prev stores aged a tile
        if constexpr (BNIN) {
            if (tn < ntiles) transformA(buf ^ 1);
            __syncthreads();          // LDS-only between barriers -> cheap drain
        }
        epilogue(t);                  // stores issue here, overlap next tile
        buf ^= 1;
        t = tn;
    }

    if constexpr (STATS) {
#pragma unroll
        for (int cf = 0; cf < 2; cf++) {
            float s = sA[cf], q = qA[cf];
            s += __shfl_xor(s, 16); s += __shfl_xor(s, 32);
            q += __shfl_xor(q, 16); q += __shfl_xor(q, 32);
            if (lane < 16) {
                int colw = colh * 128 + colg * 32 + cf * 16 + l15;
                atomicAdd(&sums[colw], s);
                atomicAdd(&sqs[colw], q);
            }
        }
    }
}

__global__ void finalize_k(const float* __restrict__ sum, const float* __restrict__ sq,
                           const float* __restrict__ g, const float* __restrict__ b,
                           float2* __restrict__ scsh2, float invN) {
    int t = threadIdx.x;
    float mean = sum[t] * invN;
    float var = sq[t] * invN - mean * mean;
    float s = g[t] * rsqrtf(var + 1e-5f);
    scsh2[t] = make_float2(s, b[t] - mean * s);
}

extern "C" void kernel_launch(void* const* d_in, const int* in_sizes, int n_in,
                              void* d_out, int out_size, void* d_ws, size_t ws_size,
                              hipStream_t stream)
{
    const int N = in_sizes[0] / 128;
    const int E = in_sizes[1] / 2;
    const float* x     = (const float*)d_in[0];
    const void*  ei    = d_in[1];
    const float* lin_w = (const float*)d_in[2];
    const float* lin_b = (const float*)d_in[3];
    const float* eps   = (const float*)d_in[4];
    const float* w1    = (const float*)d_in[5];
    const float* g1    = (const float*)d_in[6];
    const float* b1    = (const float*)d_in[7];
    const float* w2    = (const float*)d_in[8];
    const float* g2    = (const float*)d_in[9];
    const float* b2    = (const float*)d_in[10];
    const float* w3    = (const float*)d_in[11];
    const float* b3    = (const float*)d_in[12];
    float* out = (float*)d_out;

    char* ws = (char*)d_ws;
    size_t o = 0;
    auto alloc = [&](size_t bytes) -> char* {
        char* p = ws + o;
        o = (o + bytes + 255) & ~(size_t)255;
        return p;
    };
    bf16_t*   ha    = (bf16_t*)alloc((size_t)N * 256 * 2);  // [x | agg], later t2
    bf16_t*   hb    = (bf16_t*)alloc((size_t)N * 256 * 2);  // t1
    bf16_t*   wcb   = (bf16_t*)alloc((size_t)256 * 256 * 2);
    bf16_t*   w2b   = (bf16_t*)alloc((size_t)256 * 256 * 2);
    bf16_t*   w3b   = (bf16_t*)alloc((size_t)128 * 256 * 2);
    float*    bcomb = (float*)alloc(256 * 4);
    float*    stats = (float*)alloc(4 * 256 * 4);   // sum1, sq1, sum2, sq2
    float2*   scsh1 = (float2*)alloc(256 * 8);
    float2*   scsh2 = (float2*)alloc(256 * 8);
    int*      bcnt  = (int*)alloc(1024 * 4);
    int*      boffs = (int*)alloc(1025 * 4);
    int*      gcur  = (int*)alloc(1024 * 4);
    int*      offs  = (int*)alloc((size_t)(N + 1) * 4);
    unsigned* pairs = (unsigned*)alloc((size_t)E * 4);
    int*      csr   = (int*)alloc((size_t)E * 4);
    int*      flag  = (int*)alloc(4);

    const int NBK = (N + 127) >> 7;

    hipMemsetAsync(bcnt, 0, 1024 * 4, stream);
    hipMemsetAsync(stats, 0, 4 * 256 * 4, stream);
    hipMemsetAsync(flag, 0, 4, stream);

    // conversions / weight prep
    int nx8 = N * 16;
    conv_x_k<<<(nx8 + 255) / 256, 256, 0, stream>>>(x, ha, nx8);
    wcomb_k<<<256, 256, 0, stream>>>(w1, lin_w, lin_b, eps, wcb, bcomb);
    conv_k<<<32, 256, 0, stream>>>(w2, w2b, 8192);
    conv_k<<<16, 256, 0, stream>>>(w3, w3b, 4096);

    // two-level bucket sort of edges -> per-node CSR (all writes coalesced)
    const int nch = (E + CHUNK - 1) / CHUNK;
    detect_k<<<1, 256, 0, stream>>>((const int*)ei, flag);
    bhist_k<<<nch, 256, 0, stream>>>(ei, flag, E, bcnt);
    bscan_k<<<1, 1024, 0, stream>>>(bcnt, boffs, gcur, offs, NBK, N, E);
    binfill_k<<<nch, 256, 0, stream>>>(ei, flag, E, NBK, gcur, pairs);
    bsort2_k<<<NBK, 256, 0, stream>>>(pairs, boffs, offs, csr, N);
    gather_k<<<(N + 3) / 4, 256, 0, stream>>>(ha, offs, csr, N);

    const int nt64 = (N + 63) / 64;
    // t1 = [x|agg] @ Wc^T + bcomb (+ BN1 stats)
    gemm_w<2, false, true, false, true><<<256, 512, 0, stream>>>(
        ha, wcb, nullptr, stats + 0, stats + 256, bcomb, hb, nullptr, N, nt64, 128);
    finalize_k<<<1, 256, 0, stream>>>(stats + 0, stats + 256, g1, b1, scsh1, 1.f / (float)N);
    // t2 = relu(BN1(t1))@w2^T (+ BN2 stats)
    gemm_w<2, true, true, false, false><<<256, 512, 0, stream>>>(
        hb, w2b, scsh1, stats + 512, stats + 768, nullptr, ha, nullptr, N, nt64, 128);
    finalize_k<<<1, 256, 0, stream>>>(stats + 512, stats + 768, g2, b2, scsh2, 1.f / (float)N);
    // out = relu(BN2(t2))@w3^T + b3
    gemm_w<1, true, false, true, true><<<256, 512, 0, stream>>>(
        ha, w3b, scsh2, nullptr, nullptr, b3, nullptr, out, N, nt64, 256);
}

// Round 15
// 250.802 us; speedup vs baseline: 1.4273x; 1.0665x over previous
//
#include <hip/hip_runtime.h>
#include <cstdint>
#include <cstddef>

typedef __bf16 bf16_t;
typedef __bf16 bf16x8 __attribute__((ext_vector_type(8)));
typedef float f32x4 __attribute__((ext_vector_type(4)));

#define GLOBAL_AS __attribute__((address_space(1)))
#define LDS_AS    __attribute__((address_space(3)))

__device__ __forceinline__ void glds16(const void* g, void* l) {
    __builtin_amdgcn_global_load_lds((const GLOBAL_AS void*)g, (LDS_AS void*)l, 16, 0, 0);
}

// ---------------- conversions ----------------
__global__ void conv_k(const float* __restrict__ in, bf16_t* __restrict__ out, int n8) {
    int id = blockIdx.x * 256 + threadIdx.x;
    if (id >= n8) return;
    const float4* p = (const float4*)in;
    float4 a = p[2 * id], b = p[2 * id + 1];
    bf16x8 o;
    o[0] = (bf16_t)a.x; o[1] = (bf16_t)a.y; o[2] = (bf16_t)a.z; o[3] = (bf16_t)a.w;
    o[4] = (bf16_t)b.x; o[5] = (bf16_t)b.y; o[6] = (bf16_t)b.z; o[7] = (bf16_t)b.w;
    *(bf16x8*)(out + (size_t)id * 8) = o;
}

// x fp32 -> cols 0..127 of interleaved ha[N][256]
__global__ void conv_x_k(const float* __restrict__ in, bf16_t* __restrict__ ha, int n8) {
    int id = blockIdx.x * 256 + threadIdx.x;
    if (id >= n8) return;
    const float4* p = (const float4*)in;
    float4 a = p[2 * id], b = p[2 * id + 1];
    bf16x8 o;
    o[0] = (bf16_t)a.x; o[1] = (bf16_t)a.y; o[2] = (bf16_t)a.z; o[3] = (bf16_t)a.w;
    o[4] = (bf16_t)b.x; o[5] = (bf16_t)b.y; o[6] = (bf16_t)b.z; o[7] = (bf16_t)b.w;
    int row = id >> 4, ch = id & 15;
    *(bf16x8*)(ha + (size_t)row * 256 + ch * 8) = o;
}

// ---------------- merged weight: Wc = w1 @ W0, bcomb = w1 @ lin_b ----------------
__global__ void wcomb_k(const float* __restrict__ w1, const float* __restrict__ lin_w,
                        const float* __restrict__ lin_b, const float* __restrict__ eps_p,
                        bf16_t* __restrict__ wc, float* __restrict__ bcomb) {
    __shared__ float red[256];
    int c = blockIdx.x, t = threadIdx.x;
    const float* w1row = w1 + c * 256;
    float onepe = 1.f + *eps_p;
    float v;
    if (t < 128) {
        float acc = 0.f;
        for (int j = 0; j < 256; j++) acc += w1row[j] * lin_w[j * 128 + t];
        v = acc + onepe * (w1row[t] + w1row[t + 128]);
    } else {
        int m = t - 128;
        v = w1row[m] + w1row[t];
    }
    wc[c * 256 + t] = (bf16_t)v;
    red[t] = w1row[t] * lin_b[t];
    __syncthreads();
    for (int off = 128; off > 0; off >>= 1) {
        if (t < off) red[t] += red[t + off];
        __syncthreads();
    }
    if (t == 0) bcomb[c] = red[0];
}

// ---------------- edge-index dtype detection ----------------
__global__ void detect_k(const int* __restrict__ ei, int* __restrict__ flag) {
    int v = ei[2 * threadIdx.x + 1];
    if (v != 0) atomicOr(flag, 1);   // 1 => int32 layout
}

// ---------------- bucket sort of edges (bucket = dst >> 7, 128 nodes/bucket) ----------------
#define CHUNK 8192

__global__ __launch_bounds__(256) void bhist_k(const void* __restrict__ ei, const int* __restrict__ flag,
                                               int E, int* __restrict__ bcnt) {
    __shared__ int cnt[1024];
    int t = threadIdx.x;
    for (int b = t; b < 1024; b += 256) cnt[b] = 0;
    __syncthreads();
    int base = blockIdx.x * CHUNK;
    int i32 = *flag;
#pragma unroll 4
    for (int i = 0; i < CHUNK / 256; i++) {
        int e = base + t + 256 * i;
        if (e < E) {
            int dst = i32 ? ((const int*)ei)[e] : (int)((const long long*)ei)[e];
            atomicAdd(&cnt[dst >> 7], 1);
        }
    }
    __syncthreads();
    for (int b = t; b < 1024; b += 256)
        if (cnt[b]) atomicAdd(&bcnt[b], cnt[b]);
}

__global__ __launch_bounds__(1024) void bscan_k(const int* __restrict__ bcnt, int* __restrict__ boffs,
                                                int* __restrict__ gcur, int* __restrict__ offs,
                                                int NBK, int N, int E) {
    __shared__ int lds[1024];
    int t = threadIdx.x;
    int v = (t < NBK) ? bcnt[t] : 0;
    lds[t] = v;
    __syncthreads();
    for (int off = 1; off < 1024; off <<= 1) {
        int add = (t >= off) ? lds[t - off] : 0;
        __syncthreads();
        lds[t] += add;
        __syncthreads();
    }
    if (t < NBK) {
        int excl = lds[t] - v;
        boffs[t] = excl;
        gcur[t] = excl;
    }
    if (t == 0) { boffs[NBK] = E; offs[N] = E; }
}

// per-block multisplit: LDS hist -> LDS scan -> LDS placement -> coalesced flush
// (bucket id recorded at placement -> flush is a direct lookup, no binary search)
__global__ __launch_bounds__(256) void binfill_k(const void* __restrict__ ei, const int* __restrict__ flag,
                                                 int E, int NBK, int* __restrict__ gcur,
                                                 unsigned* __restrict__ pairs) {
    __shared__ int cnt[1024];
    __shared__ int pref[1024];
    __shared__ int cur[1024];
    __shared__ int gbase[1024];
    __shared__ int red[256];
    __shared__ unsigned slot[CHUNK];
    __shared__ unsigned short sbk[CHUNK];
    int t = threadIdx.x;
    int base = blockIdx.x * CHUNK;
    int chunk_n = E - base; if (chunk_n > CHUNK) chunk_n = CHUNK;
    int i32 = *flag;
    for (int b = t; b < 1024; b += 256) cnt[b] = 0;
    __syncthreads();
    // pass 1: hist
#pragma unroll 4
    for (int i = 0; i < CHUNK / 256; i++) {
        int e = base + t + 256 * i;
        if (e < E) {
            int dst = i32 ? ((const int*)ei)[e] : (int)((const long long*)ei)[e];
            atomicAdd(&cnt[dst >> 7], 1);
        }
    }
    __syncthreads();
    // scan cnt[1024] with 256 threads (4 per thread)
    int t4 = t * 4;
    int c0 = cnt[t4], c1 = cnt[t4 + 1], c2 = cnt[t4 + 2], c3 = cnt[t4 + 3];
    int s = c0 + c1 + c2 + c3;
    red[t] = s;
    __syncthreads();
    for (int off = 1; off < 256; off <<= 1) {
        int add = (t >= off) ? red[t - off] : 0;
        __syncthreads();
        red[t] += add;
        __syncthreads();
    }
    int run = red[t] - s;
    pref[t4] = run; cur[t4] = run; run += c0;
    pref[t4 + 1] = run; cur[t4 + 1] = run; run += c1;
    pref[t4 + 2] = run; cur[t4 + 2] = run; run += c2;
    pref[t4 + 3] = run; cur[t4 + 3] = run;
    __syncthreads();
    // pass 2: place into LDS slots (+ record bucket id)
#pragma unroll 4
    for (int i = 0; i < CHUNK / 256; i++) {
        int e = base + t + 256 * i;
        if (e < E) {
            int dst, src;
            if (i32) { dst = ((const int*)ei)[e]; src = ((const int*)ei)[E + e]; }
            else     { dst = (int)((const long long*)ei)[e]; src = (int)((const long long*)ei)[E + e]; }
            int b = dst >> 7;
            int p = atomicAdd(&cur[b], 1);
            slot[p] = ((unsigned)(dst & 127) << 20) | (unsigned)src;
            sbk[p] = (unsigned short)b;
        }
    }
    __syncthreads();
    // per-bucket global base
    for (int b = t; b < 1024; b += 256) {
        int c = (b + 1 < 1024) ? (pref[b + 1] - pref[b]) : (chunk_n - pref[b]);
        if (b < NBK && c > 0) gbase[b] = atomicAdd(&gcur[b], c);
    }
    __syncthreads();
    // coalesced flush: direct bucket lookup (no search)
    for (int i = t; i < chunk_n; i += 256) {
        int bk = sbk[i];
        pairs[gbase[bk] + (i - pref[bk])] = slot[i];
    }
}

// level-2 counting sort: one block per bucket -> per-node CSR + offs
__global__ __launch_bounds__(256) void bsort2_k(const unsigned* __restrict__ pairs,
                                                const int* __restrict__ boffs,
                                                int* __restrict__ offs,
                                                int* __restrict__ csr, int N) {
    __shared__ int cnt[128], pref[128], cur[128];
    int t = threadIdx.x;
    int b = blockIdx.x;
    int s = boffs[b], e = boffs[b + 1];
    if (t < 128) cnt[t] = 0;
    __syncthreads();
    for (int i = s + t; i < e; i += 256)
        atomicAdd(&cnt[pairs[i] >> 20], 1);
    __syncthreads();
    if (t < 128) pref[t] = cnt[t];
    __syncthreads();
    for (int off = 1; off < 128; off <<= 1) {
        int v = 0;
        if (t < 128 && t >= off) v = pref[t - off];
        __syncthreads();
        if (t < 128) pref[t] += v;
        __syncthreads();
    }
    if (t < 128) {
        int ex = pref[t] - cnt[t];      // exclusive prefix
        cur[t] = ex;
        int node = b * 128 + t;
        if (node < N) offs[node] = s + ex;
    }
    __syncthreads();
    for (int i = s + t; i < e; i += 256) {
        unsigned u = pairs[i];
        int dl = (int)(u >> 20);
        int p = atomicAdd(&cur[dl], 1);
        csr[s + p] = (int)(u & 0xFFFFFu);
    }
}

// one wave per node; 8 rows in flight, index prefetch one iteration ahead
__global__ __launch_bounds__(256) void gather_k(bf16_t* __restrict__ ha, const int* __restrict__ offs,
                                                const int* __restrict__ csr, int N) {
    int w = (blockIdx.x * 256 + threadIdx.x) >> 6;
    if (w >= N) return;
    int lane = threadIdx.x & 63;
    int g = lane >> 4, l15 = lane & 15;
    int s = offs[w], e = offs[w + 1];
    float acc[8] = {0.f, 0.f, 0.f, 0.f, 0.f, 0.f, 0.f, 0.f};
    float acc2[8] = {0.f, 0.f, 0.f, 0.f, 0.f, 0.f, 0.f, 0.f};
    int i = s + g;
    bool h0 = i < e, h1 = i + 4 < e;
    int p0 = h0 ? csr[i] : 0;
    int p1 = h1 ? csr[i + 4] : 0;
    while (h1) {
        int ni = i + 8;
        bool nh0 = ni < e, nh1 = ni + 4 < e;
        int np0 = nh0 ? csr[ni] : 0;
        int np1 = nh1 ? csr[ni + 4] : 0;
        bf16x8 v0 = *(const bf16x8*)(ha + (size_t)p0 * 256 + l15 * 8);
        bf16x8 v1 = *(const bf16x8*)(ha + (size_t)p1 * 256 + l15 * 8);
#pragma unroll
        for (int j = 0; j < 8; j++) { acc[j] += (float)v0[j]; acc2[j] += (float)v1[j]; }
        i = ni; p0 = np0; p1 = np1; h0 = nh0; h1 = nh1;
    }
    if (h0) {
        bf16x8 v0 = *(const bf16x8*)(ha + (size_t)p0 * 256 + l15 * 8);
#pragma unroll
        for (int j = 0; j < 8; j++) acc[j] += (float)v0[j];
    }
#pragma unroll
    for (int j = 0; j < 8; j++) {
        acc[j] += acc2[j];
        acc[j] += __shfl_xor(acc[j], 16);
        acc[j] += __shfl_xor(acc[j], 32);
    }
    if (g == 0) {
        bf16x8 o;
#pragma unroll
        for (int j = 0; j < 8; j++) o[j] = (bf16_t)acc[j];
        *(bf16x8*)(ha + (size_t)w * 256 + 128 + l15 * 8) = o;
    }
}

// ---------------- W-resident + A-LDS-tiled K=256 MFMA GEMM (v4) ----------------
// R14 structure plus:
// (1) XCD-paired colh: colh = blockIdx>>7 so the two blocks sharing A rows
//     (b, b+128; 128%8==0) land on the SAME XCD -> 2nd A read hits that L2.
// (2) Ping-pong accumulators: epilogue(t-1) issues BETWEEN stageA(t+1) and
//     compute(t) -> the barrier-drained stage gets epilogue+compute as latency
//     cover instead of compute alone.
// BNIN applied once per tile in LDS (8x dedup), per-thread scale/shift in regs.
// Swizzles (both-sides m173): A koff^=(row&7)<<4, W koff^=(col&7)<<4 (2-way=free).
// mfma_f32_16x16x32_bf16 (m89): A lane A[l&15][(l>>4)*8+i]; B lane B[k][l&15];
// D reg i <-> out[row=(l>>4)*4+i][col=l&15].
template<int NHALF, bool BNIN, bool STATS, bool FINAL, bool BIAS>
__global__ __launch_bounds__(512, 1) void gemm_w(
    const bf16_t* __restrict__ A, const bf16_t* __restrict__ W,
    const float2* __restrict__ scsh2,
    float* __restrict__ sums, float* __restrict__ sqs,
    const float* __restrict__ bias,
    bf16_t* __restrict__ Obf, float* __restrict__ Of, int N, int ntiles, int tstride)
{
    constexpr int NCOLTOT = NHALF * 128;
    __shared__ __align__(16) char smemW[65536];      // 128 cols x 512B
    __shared__ __align__(16) char smemA[2][32768];   // 2 x (64 rows x 512B)

    const int tid = threadIdx.x;
    const int lane = tid & 63, wid = tid >> 6;
    const int l15 = lane & 15, l4 = lane >> 4;
    const int rowg = wid & 1, colg = wid >> 1;       // 2 rowg x 4 colg
    const int colh = (NHALF == 2) ? (int)(blockIdx.x >> 7) : 0;   // XCD-paired
    const int rb   = (NHALF == 2) ? (int)(blockIdx.x & 127) : (int)blockIdx.x;

    // stage the W column-half (64KB) once: swizzled global source, linear LDS
#pragma unroll
    for (int it = 0; it < 8; it++) {
        int d = (it * 512 + tid) * 16;
        int col = d >> 9, koff = d & 511;
        int ksw = koff ^ ((col & 7) << 4);
        glds16((const char*)W + (size_t)(colh * 128 + col) * 512 + ksw, smemW + d);
    }

    auto stageA = [&](int buf, int t) {
        size_t rowbase = (size_t)t * 64;
#pragma unroll
        for (int it = 0; it < 4; it++) {
            int d = (it * 512 + tid) * 16;
            int row = d >> 9, koff = d & 511;
            int ksw = koff ^ ((row & 7) << 4);
            glds16((const char*)A + (rowbase + row) * 512 + ksw, smemA[buf] + d);
        }
    };

    // hoisted per-thread BN scale/shift for this thread's fixed 4x b128 LDS span
    float2 sslr[32];
    if constexpr (BNIN) {
#pragma unroll
        for (int it = 0; it < 4; it++) {
            int d = (it * 512 + tid) * 16;
            int row = d >> 9;
            int k0 = ((d & 511) ^ ((row & 7) << 4)) >> 1;
#pragma unroll
            for (int i = 0; i < 8; i++) sslr[it * 8 + i] = scsh2[k0 + i];
        }
    }

    auto transformA = [&](int buf) {
#pragma unroll
        for (int it = 0; it < 4; it++) {
            int d = (it * 512 + tid) * 16;
            bf16x8 v = *(const bf16x8*)(smemA[buf] + d);
            bf16x8 o;
#pragma unroll
            for (int i = 0; i < 8; i++) {
                float2 ss = sslr[it * 8 + i];
                o[i] = (bf16_t)fmaxf((float)v[i] * ss.x + ss.y, 0.f);
            }
            *(bf16x8*)(smemA[buf] + d) = o;
        }
    };

    float bbv[2];
    if constexpr (BIAS || FINAL) {
#pragma unroll
        for (int cf = 0; cf < 2; cf++)
            bbv[cf] = bias[colh * 128 + colg * 32 + cf * 16 + l15];
    }
    float sA[2], qA[2];
    if constexpr (STATS) { sA[0] = sA[1] = qA[0] = qA[1] = 0.f; }

    auto compute = [&](int buf, f32x4 (&acc)[2][2]) {
#pragma unroll
        for (int i = 0; i < 2; i++) { acc[i][0] = f32x4{0.f,0.f,0.f,0.f}; acc[i][1] = f32x4{0.f,0.f,0.f,0.f}; }
#pragma unroll
        for (int c = 0; c < 8; c++) {
            const int koff = c * 64 + l4 * 16;
            bf16x8 a[2];
#pragma unroll
            for (int fr = 0; fr < 2; fr++) {
                int row = rowg * 32 + fr * 16 + l15;
                a[fr] = *(const bf16x8*)(smemA[buf] + row * 512 + (koff ^ ((row & 7) << 4)));
            }
#pragma unroll
            for (int cf = 0; cf < 2; cf++) {
                int col = colg * 32 + cf * 16 + l15;
                const bf16x8 b = *(const bf16x8*)(smemW + col * 512 + (koff ^ ((col & 7) << 4)));
                acc[0][cf] = __builtin_amdgcn_mfma_f32_16x16x32_bf16(a[0], b, acc[0][cf], 0, 0, 0);
                acc[1][cf] = __builtin_amdgcn_mfma_f32_16x16x32_bf16(a[1], b, acc[1][cf], 0, 0, 0);
            }
        }
    };

    auto epilogue = [&](int t, f32x4 (&acc)[2][2]) {
        const int rows0 = t * 64 + rowg * 32;
#pragma unroll
        for (int fr = 0; fr < 2; fr++) {
            int rb0 = rows0 + fr * 16 + l4 * 4;
#pragma unroll
            for (int cf = 0; cf < 2; cf++) {
                int colw = colh * 128 + colg * 32 + cf * 16 + l15;
                f32x4 av = acc[fr][cf];
#pragma unroll
                for (int i = 0; i < 4; i++) {
                    int r = rb0 + i;
                    if constexpr (FINAL) {
                        if (r < N) Of[(size_t)r * NCOLTOT + colw] = av[i] + bbv[cf];
                    } else {
                        float v = av[i];
                        if constexpr (BIAS) v += bbv[cf];
                        bf16_t hv = (bf16_t)v;
                        if (r < N) Obf[(size_t)r * 256 + colw] = hv;
                        if constexpr (STATS) {
                            float vv = (r < N) ? (float)hv : 0.f;
                            sA[cf] += vv; qA[cf] += vv * vv;
                        }
                    }
                }
            }
        }
    };

    f32x4 accP[2][2], accQ[2][2];
    int t = rb, buf = 0;
    if (t < ntiles) stageA(0, t);
    __syncthreads();                  // W + first A staged
    if constexpr (BNIN) {
        if (t < ntiles) transformA(0);
        __syncthreads();
    }

    int tprev = -1;
    bool ping = true;
    while (t < ntiles) {
        int tn = t + tstride;
        if (tn < ntiles) stageA(buf ^ 1, tn);
        if (tprev >= 0) {             // previous tile's stores: cover for the stage
            if (ping) epilogue(tprev, accQ); else epilogue(tprev, accP);
        }
        if (ping) compute(buf, accP); else compute(buf, accQ);
        __syncthreads();              // drains stage(buf^1), aged by epilogue+compute
        if constexpr (BNIN) {
            if (tn < ntiles) transformA(buf ^ 1);
            __syncthreads();          // LDS-only -> cheap drain
        }
        tprev = t; t = tn; buf ^= 1; ping = !ping;
    }
    if (tprev >= 0) {
        if (ping) epilogue(tprev, accQ); else epilogue(tprev, accP);
    }

    if constexpr (STATS) {
#pragma unroll
        for (int cf = 0; cf < 2; cf++) {
            float s = sA[cf], q = qA[cf];
            s += __shfl_xor(s, 16); s += __shfl_xor(s, 32);
            q += __shfl_xor(q, 16); q += __shfl_xor(q, 32);
            if (lane < 16) {
                int colw = colh * 128 + colg * 32 + cf * 16 + l15;
                atomicAdd(&sums[colw], s);
                atomicAdd(&sqs[colw], q);
            }
        }
    }
}

__global__ void finalize_k(const float* __restrict__ sum, const float* __restrict__ sq,
                           const float* __restrict__ g, const float* __restrict__ b,
                           float2* __restrict__ scsh2, float invN) {
    int t = threadIdx.x;
    float mean = sum[t] * invN;
    float var = sq[t] * invN - mean * mean;
    float s = g[t] * rsqrtf(var + 1e-5f);
    scsh2[t] = make_float2(s, b[t] - mean * s);
}

extern "C" void kernel_launch(void* const* d_in, const int* in_sizes, int n_in,
                              void* d_out, int out_size, void* d_ws, size_t ws_size,
                              hipStream_t stream)
{
    const int N = in_sizes[0] / 128;
    const int E = in_sizes[1] / 2;
    const float* x     = (const float*)d_in[0];
    const void*  ei    = d_in[1];
    const float* lin_w = (const float*)d_in[2];
    const float* lin_b = (const float*)d_in[3];
    const float* eps   = (const float*)d_in[4];
    const float* w1    = (const float*)d_in[5];
    const float* g1    = (const float*)d_in[6];
    const float* b1    = (const float*)d_in[7];
    const float* w2    = (const float*)d_in[8];
    const float* g2    = (const float*)d_in[9];
    const float* b2    = (const float*)d_in[10];
    const float* w3    = (const float*)d_in[11];
    const float* b3    = (const float*)d_in[12];
    float* out = (float*)d_out;

    char* ws = (char*)d_ws;
    size_t o = 0;
    auto alloc = [&](size_t bytes) -> char* {
        char* p = ws + o;
        o = (o + bytes + 255) & ~(size_t)255;
        return p;
    };
    bf16_t*   ha    = (bf16_t*)alloc((size_t)N * 256 * 2);  // [x | agg], later t2
    bf16_t*   hb    = (bf16_t*)alloc((size_t)N * 256 * 2);  // t1
    bf16_t*   wcb   = (bf16_t*)alloc((size_t)256 * 256 * 2);
    bf16_t*   w2b   = (bf16_t*)alloc((size_t)256 * 256 * 2);
    bf16_t*   w3b   = (bf16_t*)alloc((size_t)128 * 256 * 2);
    float*    bcomb = (float*)alloc(256 * 4);
    float*    stats = (float*)alloc(4 * 256 * 4);   // sum1, sq1, sum2, sq2
    float2*   scsh1 = (float2*)alloc(256 * 8);
    float2*   scsh2 = (float2*)alloc(256 * 8);
    int*      bcnt  = (int*)alloc(1024 * 4);
    int*      boffs = (int*)alloc(1025 * 4);
    int*      gcur  = (int*)alloc(1024 * 4);
    int*      offs  = (int*)alloc((size_t)(N + 1) * 4);
    unsigned* pairs = (unsigned*)alloc((size_t)E * 4);
    int*      csr   = (int*)alloc((size_t)E * 4);
    int*      flag  = (int*)alloc(4);

    const int NBK = (N + 127) >> 7;

    hipMemsetAsync(bcnt, 0, 1024 * 4, stream);
    hipMemsetAsync(stats, 0, 4 * 256 * 4, stream);
    hipMemsetAsync(flag, 0, 4, stream);

    // conversions / weight prep
    int nx8 = N * 16;
    conv_x_k<<<(nx8 + 255) / 256, 256, 0, stream>>>(x, ha, nx8);
    wcomb_k<<<256, 256, 0, stream>>>(w1, lin_w, lin_b, eps, wcb, bcomb);
    conv_k<<<32, 256, 0, stream>>>(w2, w2b, 8192);
    conv_k<<<16, 256, 0, stream>>>(w3, w3b, 4096);

    // two-level bucket sort of edges -> per-node CSR (all writes coalesced)
    const int nch = (E + CHUNK - 1) / CHUNK;
    detect_k<<<1, 256, 0, stream>>>((const int*)ei, flag);
    bhist_k<<<nch, 256, 0, stream>>>(ei, flag, E, bcnt);
    bscan_k<<<1, 1024, 0, stream>>>(bcnt, boffs, gcur, offs, NBK, N, E);
    binfill_k<<<nch, 256, 0, stream>>>(ei, flag, E, NBK, gcur, pairs);
    bsort2_k<<<NBK, 256, 0, stream>>>(pairs, boffs, offs, csr, N);
    gather_k<<<(N + 3) / 4, 256, 0, stream>>>(ha, offs, csr, N);

    const int nt64 = (N + 63) / 64;
    // t1 = [x|agg] @ Wc^T + bcomb (+ BN1 stats)
    gemm_w<2, false, true, false, true><<<256, 512, 0, stream>>>(
        ha, wcb, nullptr, stats + 0, stats + 256, bcomb, hb, nullptr, N, nt64, 128);
    finalize_k<<<1, 256, 0, stream>>>(stats + 0, stats + 256, g1, b1, scsh1, 1.f / (float)N);
    // t2 = relu(BN1(t1))@w2^T (+ BN2 stats)
    gemm_w<2, true, true, false, false><<<256, 512, 0, stream>>>(
        hb, w2b, scsh1, stats + 512, stats + 768, nullptr, ha, nullptr, N, nt64, 128);
    finalize_k<<<1, 256, 0, stream>>>(stats + 512, stats + 768, g2, b2, scsh2, 1.f / (float)N);
    // out = relu(BN2(t2))@w3^T + b3
    gemm_w<1, true, false, true, true><<<256, 512, 0, stream>>>(
        ha, w3b, scsh2, nullptr, nullptr, b3, nullptr, out, N, nt64, 256);
}

// Round 16
// 242.538 us; speedup vs baseline: 1.4759x; 1.0341x over previous
//
#include <hip/hip_runtime.h>
#include <cstdint>
#include <cstddef>

typedef __bf16 bf16_t;
typedef __bf16 bf16x8 __attribute__((ext_vector_type(8)));
typedef float f32x4 __attribute__((ext_vector_type(4)));

#define GLOBAL_AS __attribute__((address_space(1)))
#define LDS_AS    __attribute__((address_space(3)))

__device__ __forceinline__ void glds16(const void* g, void* l) {
    __builtin_amdgcn_global_load_lds((const GLOBAL_AS void*)g, (LDS_AS void*)l, 16, 0, 0);
}

// ---------------- conversions ----------------
__global__ void conv_k(const float* __restrict__ in, bf16_t* __restrict__ out, int n8) {
    int id = blockIdx.x * 256 + threadIdx.x;
    if (id >= n8) return;
    const float4* p = (const float4*)in;
    float4 a = p[2 * id], b = p[2 * id + 1];
    bf16x8 o;
    o[0] = (bf16_t)a.x; o[1] = (bf16_t)a.y; o[2] = (bf16_t)a.z; o[3] = (bf16_t)a.w;
    o[4] = (bf16_t)b.x; o[5] = (bf16_t)b.y; o[6] = (bf16_t)b.z; o[7] = (bf16_t)b.w;
    *(bf16x8*)(out + (size_t)id * 8) = o;
}

// x fp32 -> cols 0..127 of interleaved ha[N][256]
__global__ void conv_x_k(const float* __restrict__ in, bf16_t* __restrict__ ha, int n8) {
    int id = blockIdx.x * 256 + threadIdx.x;
    if (id >= n8) return;
    const float4* p = (const float4*)in;
    float4 a = p[2 * id], b = p[2 * id + 1];
    bf16x8 o;
    o[0] = (bf16_t)a.x; o[1] = (bf16_t)a.y; o[2] = (bf16_t)a.z; o[3] = (bf16_t)a.w;
    o[4] = (bf16_t)b.x; o[5] = (bf16_t)b.y; o[6] = (bf16_t)b.z; o[7] = (bf16_t)b.w;
    int row = id >> 4, ch = id & 15;
    *(bf16x8*)(ha + (size_t)row * 256 + ch * 8) = o;
}

// ---------------- merged weight: Wc = w1 @ W0, bcomb = w1 @ lin_b ----------------
__global__ void wcomb_k(const float* __restrict__ w1, const float* __restrict__ lin_w,
                        const float* __restrict__ lin_b, const float* __restrict__ eps_p,
                        bf16_t* __restrict__ wc, float* __restrict__ bcomb) {
    __shared__ float red[256];
    int c = blockIdx.x, t = threadIdx.x;
    const float* w1row = w1 + c * 256;
    float onepe = 1.f + *eps_p;
    float v;
    if (t < 128) {
        float acc = 0.f;
        for (int j = 0; j < 256; j++) acc += w1row[j] * lin_w[j * 128 + t];
        v = acc + onepe * (w1row[t] + w1row[t + 128]);
    } else {
        int m = t - 128;
        v = w1row[m] + w1row[t];
    }
    wc[c * 256 + t] = (bf16_t)v;
    red[t] = w1row[t] * lin_b[t];
    __syncthreads();
    for (int off = 128; off > 0; off >>= 1) {
        if (t < off) red[t] += red[t + off];
        __syncthreads();
    }
    if (t == 0) bcomb[c] = red[0];
}

// ---------------- edge-index dtype detection ----------------
__global__ void detect_k(const int* __restrict__ ei, int* __restrict__ flag) {
    int v = ei[2 * threadIdx.x + 1];
    if (v != 0) atomicOr(flag, 1);   // 1 => int32 layout
}

// ---------------- bucket sort of edges (bucket = dst >> 7, 128 nodes/bucket) ----------------
#define CHUNK 8192

__global__ __launch_bounds__(256) void bhist_k(const void* __restrict__ ei, const int* __restrict__ flag,
                                               int E, int* __restrict__ bcnt) {
    __shared__ int cnt[1024];
    int t = threadIdx.x;
    for (int b = t; b < 1024; b += 256) cnt[b] = 0;
    __syncthreads();
    int base = blockIdx.x * CHUNK;
    int i32 = *flag;
#pragma unroll 4
    for (int i = 0; i < CHUNK / 256; i++) {
        int e = base + t + 256 * i;
        if (e < E) {
            int dst = i32 ? ((const int*)ei)[e] : (int)((const long long*)ei)[e];
            atomicAdd(&cnt[dst >> 7], 1);
        }
    }
    __syncthreads();
    for (int b = t; b < 1024; b += 256)
        if (cnt[b]) atomicAdd(&bcnt[b], cnt[b]);
}

__global__ __launch_bounds__(1024) void bscan_k(const int* __restrict__ bcnt, int* __restrict__ boffs,
                                                int* __restrict__ gcur, int* __restrict__ offs,
                                                int NBK, int N, int E) {
    __shared__ int lds[1024];
    int t = threadIdx.x;
    int v = (t < NBK) ? bcnt[t] : 0;
    lds[t] = v;
    __syncthreads();
    for (int off = 1; off < 1024; off <<= 1) {
        int add = (t >= off) ? lds[t - off] : 0;
        __syncthreads();
        lds[t] += add;
        __syncthreads();
    }
    if (t < NBK) {
        int excl = lds[t] - v;
        boffs[t] = excl;
        gcur[t] = excl;
    }
    if (t == 0) { boffs[NBK] = E; offs[N] = E; }
}

// per-block multisplit: LDS hist -> LDS scan -> LDS placement -> coalesced flush
__global__ __launch_bounds__(256) void binfill_k(const void* __restrict__ ei, const int* __restrict__ flag,
                                                 int E, int NBK, int* __restrict__ gcur,
                                                 unsigned* __restrict__ pairs) {
    __shared__ int cnt[1024];
    __shared__ int pref[1024];
    __shared__ int cur[1024];
    __shared__ int gbase[1024];
    __shared__ int red[256];
    __shared__ unsigned slot[CHUNK];
    __shared__ unsigned short sbk[CHUNK];
    int t = threadIdx.x;
    int base = blockIdx.x * CHUNK;
    int chunk_n = E - base; if (chunk_n > CHUNK) chunk_n = CHUNK;
    int i32 = *flag;
    for (int b = t; b < 1024; b += 256) cnt[b] = 0;
    __syncthreads();
    // pass 1: hist
#pragma unroll 4
    for (int i = 0; i < CHUNK / 256; i++) {
        int e = base + t + 256 * i;
        if (e < E) {
            int dst = i32 ? ((const int*)ei)[e] : (int)((const long long*)ei)[e];
            atomicAdd(&cnt[dst >> 7], 1);
        }
    }
    __syncthreads();
    // scan cnt[1024] with 256 threads (4 per thread)
    int t4 = t * 4;
    int c0 = cnt[t4], c1 = cnt[t4 + 1], c2 = cnt[t4 + 2], c3 = cnt[t4 + 3];
    int s = c0 + c1 + c2 + c3;
    red[t] = s;
    __syncthreads();
    for (int off = 1; off < 256; off <<= 1) {
        int add = (t >= off) ? red[t - off] : 0;
        __syncthreads();
        red[t] += add;
        __syncthreads();
    }
    int run = red[t] - s;
    pref[t4] = run; cur[t4] = run; run += c0;
    pref[t4 + 1] = run; cur[t4 + 1] = run; run += c1;
    pref[t4 + 2] = run; cur[t4 + 2] = run; run += c2;
    pref[t4 + 3] = run; cur[t4 + 3] = run;
    __syncthreads();
    // pass 2: place into LDS slots (+ record bucket id)
#pragma unroll 4
    for (int i = 0; i < CHUNK / 256; i++) {
        int e = base + t + 256 * i;
        if (e < E) {
            int dst, src;
            if (i32) { dst = ((const int*)ei)[e]; src = ((const int*)ei)[E + e]; }
            else     { dst = (int)((const long long*)ei)[e]; src = (int)((const long long*)ei)[E + e]; }
            int b = dst >> 7;
            int p = atomicAdd(&cur[b], 1);
            slot[p] = ((unsigned)(dst & 127) << 20) | (unsigned)src;
            sbk[p] = (unsigned short)b;
        }
    }
    __syncthreads();
    // per-bucket global base
    for (int b = t; b < 1024; b += 256) {
        int c = (b + 1 < 1024) ? (pref[b + 1] - pref[b]) : (chunk_n - pref[b]);
        if (b < NBK && c > 0) gbase[b] = atomicAdd(&gcur[b], c);
    }
    __syncthreads();
    // coalesced flush: direct bucket lookup (no search)
    for (int i = t; i < chunk_n; i += 256) {
        int bk = sbk[i];
        pairs[gbase[bk] + (i - pref[bk])] = slot[i];
    }
}

// level-2 counting sort: one block per bucket -> per-node CSR + offs
__global__ __launch_bounds__(256) void bsort2_k(const unsigned* __restrict__ pairs,
                                                const int* __restrict__ boffs,
                                                int* __restrict__ offs,
                                                int* __restrict__ csr, int N) {
    __shared__ int cnt[128], pref[128], cur[128];
    int t = threadIdx.x;
    int b = blockIdx.x;
    int s = boffs[b], e = boffs[b + 1];
    if (t < 128) cnt[t] = 0;
    __syncthreads();
    for (int i = s + t; i < e; i += 256)
        atomicAdd(&cnt[pairs[i] >> 20], 1);
    __syncthreads();
    if (t < 128) pref[t] = cnt[t];
    __syncthreads();
    for (int off = 1; off < 128; off <<= 1) {
        int v = 0;
        if (t < 128 && t >= off) v = pref[t - off];
        __syncthreads();
        if (t < 128) pref[t] += v;
        __syncthreads();
    }
    if (t < 128) {
        int ex = pref[t] - cnt[t];      // exclusive prefix
        cur[t] = ex;
        int node = b * 128 + t;
        if (node < N) offs[node] = s + ex;
    }
    __syncthreads();
    for (int i = s + t; i < e; i += 256) {
        unsigned u = pairs[i];
        int dl = (int)(u >> 20);
        int p = atomicAdd(&cur[dl], 1);
        csr[s + p] = (int)(u & 0xFFFFFu);
    }
}

// one wave per node; 8 rows in flight, index prefetch one iteration ahead
__global__ __launch_bounds__(256) void gather_k(bf16_t* __restrict__ ha, const int* __restrict__ offs,
                                                const int* __restrict__ csr, int N) {
    int w = (blockIdx.x * 256 + threadIdx.x) >> 6;
    if (w >= N) return;
    int lane = threadIdx.x & 63;
    int g = lane >> 4, l15 = lane & 15;
    int s = offs[w], e = offs[w + 1];
    float acc[8] = {0.f, 0.f, 0.f, 0.f, 0.f, 0.f, 0.f, 0.f};
    float acc2[8] = {0.f, 0.f, 0.f, 0.f, 0.f, 0.f, 0.f, 0.f};
    int i = s + g;
    bool h0 = i < e, h1 = i + 4 < e;
    int p0 = h0 ? csr[i] : 0;
    int p1 = h1 ? csr[i + 4] : 0;
    while (h1) {
        int ni = i + 8;
        bool nh0 = ni < e, nh1 = ni + 4 < e;
        int np0 = nh0 ? csr[ni] : 0;
        int np1 = nh1 ? csr[ni + 4] : 0;
        bf16x8 v0 = *(const bf16x8*)(ha + (size_t)p0 * 256 + l15 * 8);
        bf16x8 v1 = *(const bf16x8*)(ha + (size_t)p1 * 256 + l15 * 8);
#pragma unroll
        for (int j = 0; j < 8; j++) { acc[j] += (float)v0[j]; acc2[j] += (float)v1[j]; }
        i = ni; p0 = np0; p1 = np1; h0 = nh0; h1 = nh1;
    }
    if (h0) {
        bf16x8 v0 = *(const bf16x8*)(ha + (size_t)p0 * 256 + l15 * 8);
#pragma unroll
        for (int j = 0; j < 8; j++) acc[j] += (float)v0[j];
    }
#pragma unroll
    for (int j = 0; j < 8; j++) {
        acc[j] += acc2[j];
        acc[j] += __shfl_xor(acc[j], 16);
        acc[j] += __shfl_xor(acc[j], 32);
    }
    if (g == 0) {
        bf16x8 o;
#pragma unroll
        for (int j = 0; j < 8; j++) o[j] = (bf16_t)acc[j];
        *(bf16x8*)(ha + (size_t)w * 256 + 128 + l15 * 8) = o;
    }
}

// ---------------- W-quarter-stationary + A-streamed K=256 MFMA GEMM (v5) ----------------
// LDS cut to 64KB/block (W quarter 64colsx512B = 32KB stationary + A single
// buffer 64rowsx512B = 32KB) -> 2 blocks/CU, 16 waves/CU (was 1 block, 8
// waves). A is single-buffered; the stage drain of one block is covered by the
// OTHER resident block's compute (m114 cross-block overlap — unavailable at 1
// block/CU). Column quarters x4 (x2 FINAL) read identical A rows; the quartet
// {rb, rb+T, rb+2T, rb+3T} (T%8==0) lands on ONE XCD -> 3 of 4 reads are L2
// hits (R15-proven: FETCH stays ~26MB). 8 waves = 2 rowg x 4 colg; wave tile
// 32 rows x 16 cols; 16 MFMA + 24 ds_read_b128 per tile. BNIN transform once
// per staged tile (all 512 threads), per-thread scale/shift in 32 regs.
// Swizzles (both-sides m173): A koff^=(row&7)<<4, W koff^=(col&7)<<4 (2-way=free).
// __launch_bounds__(512,4) caps VGPR at 128 (kernel needs ~80; no ping-pong).
// mfma_f32_16x16x32_bf16 (m89): A lane A[l&15][(l>>4)*8+i]; B lane B[k][l&15];
// D reg i <-> out[row=(l>>4)*4+i][col=l&15].
template<int NCOLTOT, bool BNIN, bool STATS, bool FINAL, bool BIAS>
__global__ __launch_bounds__(512, 4) void gemm_q(
    const bf16_t* __restrict__ A, const bf16_t* __restrict__ W,
    const float2* __restrict__ scsh2,
    float* __restrict__ sums, float* __restrict__ sqs,
    const float* __restrict__ bias,
    bf16_t* __restrict__ Obf, float* __restrict__ Of, int N, int ntiles, int shift)
{
    __shared__ __align__(16) char smemW[32768];      // 64 cols x 512B, stationary
    __shared__ __align__(16) char smemA[32768];      // 64 rows x 512B, streamed

    const int tid = threadIdx.x;
    const int lane = tid & 63, wid = tid >> 6;
    const int l15 = lane & 15, l4 = lane >> 4;
    const int rowg = wid & 1, colg = wid >> 1;       // 2 rowg x 4 colg
    const int tstride = 1 << shift;
    const int colq = (int)blockIdx.x >> shift;
    const int rb = (int)blockIdx.x & (tstride - 1);

    // stage the W quarter (64 cols) once: swizzled global source, linear LDS
#pragma unroll
    for (int it = 0; it < 4; it++) {
        int d = (it * 512 + tid) * 16;
        int col = d >> 9, koff = d & 511;
        int ksw = koff ^ ((col & 7) << 4);
        glds16((const char*)W + (size_t)(colq * 64 + col) * 512 + ksw, smemW + d);
    }

    auto stageA = [&](int t) {
        size_t rowbase = (size_t)t * 64;
#pragma unroll
        for (int it = 0; it < 4; it++) {
            int d = (it * 512 + tid) * 16;
            int row = d >> 9, koff = d & 511;
            int ksw = koff ^ ((row & 7) << 4);
            glds16((const char*)A + (rowbase + row) * 512 + ksw, smemA + d);
        }
    };

    // hoisted per-thread BN scale/shift for this thread's fixed 4x b128 LDS span
    float2 sslr[32];
    if constexpr (BNIN) {
#pragma unroll
        for (int it = 0; it < 4; it++) {
            int d = (it * 512 + tid) * 16;
            int row = d >> 9;
            int k0 = ((d & 511) ^ ((row & 7) << 4)) >> 1;
#pragma unroll
            for (int i = 0; i < 8; i++) sslr[it * 8 + i] = scsh2[k0 + i];
        }
    }

    auto transformA = [&]() {
#pragma unroll
        for (int it = 0; it < 4; it++) {
            int d = (it * 512 + tid) * 16;
            bf16x8 v = *(const bf16x8*)(smemA + d);
            bf16x8 o;
#pragma unroll
            for (int i = 0; i < 8; i++) {
                float2 ss = sslr[it * 8 + i];
                o[i] = (bf16_t)fmaxf((float)v[i] * ss.x + ss.y, 0.f);
            }
            *(bf16x8*)(smemA + d) = o;
        }
    };

    const int colw = colq * 64 + colg * 16 + l15;
    float bbv = 0.f;
    if constexpr (BIAS || FINAL) bbv = bias[colw];
    float sA = 0.f, qA = 0.f;

    f32x4 acc[2];

    auto compute = [&]() {
        acc[0] = f32x4{0.f, 0.f, 0.f, 0.f};
        acc[1] = f32x4{0.f, 0.f, 0.f, 0.f};
        const int col = colg * 16 + l15;
        const int wsw = (col & 7) << 4;
#pragma unroll
        for (int c = 0; c < 8; c++) {
            const int koff = c * 64 + l4 * 16;
            bf16x8 a0, a1;
            {
                int row = rowg * 32 + l15;
                a0 = *(const bf16x8*)(smemA + row * 512 + (koff ^ ((row & 7) << 4)));
                row += 16;
                a1 = *(const bf16x8*)(smemA + row * 512 + (koff ^ ((row & 7) << 4)));
            }
            const bf16x8 b = *(const bf16x8*)(smemW + col * 512 + (koff ^ wsw));
            acc[0] = __builtin_amdgcn_mfma_f32_16x16x32_bf16(a0, b, acc[0], 0, 0, 0);
            acc[1] = __builtin_amdgcn_mfma_f32_16x16x32_bf16(a1, b, acc[1], 0, 0, 0);
        }
    };

    auto epilogue = [&](int t) {
        const int rows0 = t * 64 + rowg * 32;
#pragma unroll
        for (int fr = 0; fr < 2; fr++) {
            int rb0 = rows0 + fr * 16 + l4 * 4;
            f32x4 av = acc[fr];
#pragma unroll
            for (int i = 0; i < 4; i++) {
                int r = rb0 + i;
                if constexpr (FINAL) {
                    if (r < N) Of[(size_t)r * NCOLTOT + colw] = av[i] + bbv;
                } else {
                    float v = av[i];
                    if constexpr (BIAS) v += bbv;
                    bf16_t hv = (bf16_t)v;
                    if (r < N) Obf[(size_t)r * 256 + colw] = hv;
                    if constexpr (STATS) {
                        float vv = (r < N) ? (float)hv : 0.f;
                        sA += vv; qA += vv * vv;
                    }
                }
            }
        }
    };

    int t = rb;
    if (t < ntiles) stageA(t);
    __syncthreads();                  // W + first A staged
    if constexpr (BNIN) {
        if (t < ntiles) transformA();
        __syncthreads();
    }

    while (t < ntiles) {
        compute();
        __syncthreads();              // all waves done reading smemA
        int tn = t + tstride;
        if (tn < ntiles) stageA(tn);  // overwrite smemA (safe post-barrier)
        epilogue(t);                  // stores overlap the stage latency
        __syncthreads();              // drain stage; covered by co-resident block
        if constexpr (BNIN) {
            if (tn < ntiles) transformA();
            __syncthreads();          // LDS-only -> cheap drain
        }
        t = tn;
    }

    if constexpr (STATS) {
        sA += __shfl_xor(sA, 16); sA += __shfl_xor(sA, 32);
        qA += __shfl_xor(qA, 16); qA += __shfl_xor(qA, 32);
        if (lane < 16) {
            atomicAdd(&sums[colw], sA);
            atomicAdd(&sqs[colw], qA);
        }
    }
}

__global__ void finalize_k(const float* __restrict__ sum, const float* __restrict__ sq,
                           const float* __restrict__ g, const float* __restrict__ b,
                           float2* __restrict__ scsh2, float invN) {
    int t = threadIdx.x;
    float mean = sum[t] * invN;
    float var = sq[t] * invN - mean * mean;
    float s = g[t] * rsqrtf(var + 1e-5f);
    scsh2[t] = make_float2(s, b[t] - mean * s);
}

extern "C" void kernel_launch(void* const* d_in, const int* in_sizes, int n_in,
                              void* d_out, int out_size, void* d_ws, size_t ws_size,
                              hipStream_t stream)
{
    const int N = in_sizes[0] / 128;
    const int E = in_sizes[1] / 2;
    const float* x     = (const float*)d_in[0];
    const void*  ei    = d_in[1];
    const float* lin_w = (const float*)d_in[2];
    const float* lin_b = (const float*)d_in[3];
    const float* eps   = (const float*)d_in[4];
    const float* w1    = (const float*)d_in[5];
    const float* g1    = (const float*)d_in[6];
    const float* b1    = (const float*)d_in[7];
    const float* w2    = (const float*)d_in[8];
    const float* g2    = (const float*)d_in[9];
    const float* b2    = (const float*)d_in[10];
    const float* w3    = (const float*)d_in[11];
    const float* b3    = (const float*)d_in[12];
    float* out = (float*)d_out;

    char* ws = (char*)d_ws;
    size_t o = 0;
    auto alloc = [&](size_t bytes) -> char* {
        char* p = ws + o;
        o = (o + bytes + 255) & ~(size_t)255;
        return p;
    };
    bf16_t*   ha    = (bf16_t*)alloc((size_t)N * 256 * 2);  // [x | agg], later t2
    bf16_t*   hb    = (bf16_t*)alloc((size_t)N * 256 * 2);  // t1
    bf16_t*   wcb   = (bf16_t*)alloc((size_t)256 * 256 * 2);
    bf16_t*   w2b   = (bf16_t*)alloc((size_t)256 * 256 * 2);
    bf16_t*   w3b   = (bf16_t*)alloc((size_t)128 * 256 * 2);
    float*    bcomb = (float*)alloc(256 * 4);
    float*    stats = (float*)alloc(4 * 256 * 4);   // sum1, sq1, sum2, sq2
    float2*   scsh1 = (float2*)alloc(256 * 8);
    float2*   scsh2 = (float2*)alloc(256 * 8);
    int*      bcnt  = (int*)alloc(1024 * 4);
    int*      boffs = (int*)alloc(1025 * 4);
    int*      gcur  = (int*)alloc(1024 * 4);
    int*      offs  = (int*)alloc((size_t)(N + 1) * 4);
    unsigned* pairs = (unsigned*)alloc((size_t)E * 4);
    int*      csr   = (int*)alloc((size_t)E * 4);
    int*      flag  = (int*)alloc(4);

    const int NBK = (N + 127) >> 7;

    hipMemsetAsync(bcnt, 0, 1024 * 4, stream);
    hipMemsetAsync(stats, 0, 4 * 256 * 4, stream);
    hipMemsetAsync(flag, 0, 4, stream);

    // conversions / weight prep
    int nx8 = N * 16;
    conv_x_k<<<(nx8 + 255) / 256, 256, 0, stream>>>(x, ha, nx8);
    wcomb_k<<<256, 256, 0, stream>>>(w1, lin_w, lin_b, eps, wcb, bcomb);
    conv_k<<<32, 256, 0, stream>>>(w2, w2b, 8192);
    conv_k<<<16, 256, 0, stream>>>(w3, w3b, 4096);

    // two-level bucket sort of edges -> per-node CSR (all writes coalesced)
    const int nch = (E + CHUNK - 1) / CHUNK;
    detect_k<<<1, 256, 0, stream>>>((const int*)ei, flag);
    bhist_k<<<nch, 256, 0, stream>>>(ei, flag, E, bcnt);
    bscan_k<<<1, 1024, 0, stream>>>(bcnt, boffs, gcur, offs, NBK, N, E);
    binfill_k<<<nch, 256, 0, stream>>>(ei, flag, E, NBK, gcur, pairs);
    bsort2_k<<<NBK, 256, 0, stream>>>(pairs, boffs, offs, csr, N);
    gather_k<<<(N + 3) / 4, 256, 0, stream>>>(ha, offs, csr, N);

    const int nt64 = (N + 63) / 64;
    // t1 = [x|agg] @ Wc^T + bcomb (+ BN1 stats): 4 col-quarters x 128 row-strides
    gemm_q<256, false, true, false, true><<<512, 512, 0, stream>>>(
        ha, wcb, nullptr, stats + 0, stats + 256, bcomb, hb, nullptr, N, nt64, 7);
    finalize_k<<<1, 256, 0, stream>>>(stats + 0, stats + 256, g1, b1, scsh1, 1.f / (float)N);
    // t2 = relu(BN1(t1))@w2^T (+ BN2 stats)
    gemm_q<256, true, true, false, false><<<512, 512, 0, stream>>>(
        hb, w2b, scsh1, stats + 512, stats + 768, nullptr, ha, nullptr, N, nt64, 7);
    finalize_k<<<1, 256, 0, stream>>>(stats + 512, stats + 768, g2, b2, scsh2, 1.f / (float)N);
    // out = relu(BN2(t2))@w3^T + b3: 2 col-quarters x 256 row-strides
    gemm_q<128, true, false, true, true><<<512, 512, 0, stream>>>(
        ha, w3b, scsh2, nullptr, nullptr, b3, nullptr, out, N, nt64, 8);
}